// Round 6
// baseline (326.313 us; speedup 1.0000x reference)
//
#include <hip/hip_runtime.h>
#include <hip/hip_bf16.h>

#define SQ   2048
#define DIMM 1536
#define QS   4608          // fused qkv row stride
#define NH   12
#define DH   128
#define NQB  16
#define NKB  32
#define KSEL 7

typedef unsigned short u16;
typedef __bf16 bf16x8 __attribute__((ext_vector_type(8)));
typedef _Float16 f16x8 __attribute__((ext_vector_type(8)));
typedef short  s16x8  __attribute__((ext_vector_type(8)));
typedef float  f32x4  __attribute__((ext_vector_type(4)));
typedef u16    u16x4  __attribute__((ext_vector_type(4)));

__device__ __forceinline__ float bf2f(u16 u) {
  unsigned int x = ((unsigned int)u) << 16;
  return __builtin_bit_cast(float, x);
}
__device__ __forceinline__ u16 f2bf(float f) {
  unsigned int x = __builtin_bit_cast(unsigned int, f);
  x += 0x7fffu + ((x >> 16) & 1u);
  return (u16)(x >> 16);
}

typedef __attribute__((address_space(3))) void lds_vt;
typedef const __attribute__((address_space(1))) void g_vt;
__device__ __forceinline__ void dma16(const void* g, void* l) {
  __builtin_amdgcn_global_load_lds((g_vt*)g, (lds_vt*)l, 16, 0, 0);
}

// ---------------- merged prep: hs hi/lo split + W transpose ---------------
__global__ __launch_bounds__(256) void prep_all(const float* __restrict__ hs,
                                                u16* __restrict__ hh,
                                                u16* __restrict__ hl,
                                                const float* __restrict__ W0,
                                                const float* __restrict__ W1,
                                                const float* __restrict__ W2,
                                                const float* __restrict__ W3,
                                                u16* __restrict__ WTh,
                                                u16* __restrict__ WTl) {
  __shared__ float tile[64][65];
  int bx = blockIdx.x;
  if (bx < 1536) {
    size_t i = ((size_t)bx * 256 + threadIdx.x) * 8;
    f32x4 a = *(const f32x4*)&hs[i];
    f32x4 b = *(const f32x4*)&hs[i + 4];
    s16x8 h, l;
    #pragma unroll
    for (int j = 0; j < 4; j++) {
      u16 hj = f2bf(a[j]); h[j] = (short)hj; l[j] = (short)f2bf(a[j] - bf2f(hj));
      u16 hk = f2bf(b[j]); h[4 + j] = (short)hk; l[4 + j] = (short)f2bf(b[j] - bf2f(hk));
    }
    *(s16x8*)&hh[i] = h;
    *(s16x8*)&hl[i] = l;
    return;
  }
  int b2 = bx - 1536;                  // 0..2303
  int wi = b2 / 576;
  int rest = b2 % 576;
  int k0 = (rest / 24) * 64, n0 = (rest % 24) * 64;
  const float* W = (wi == 0) ? W0 : (wi == 1) ? W1 : (wi == 2) ? W2 : W3;
  int x = threadIdx.x & 63, y = threadIdx.x >> 6;   // 64 x 4
  #pragma unroll
  for (int i = 0; i < 16; i++) {
    int k = y + i * 4;
    tile[k][x] = W[(size_t)(k0 + k) * DIMM + n0 + x];
  }
  __syncthreads();
  size_t obase = (size_t)wi * DIMM * DIMM;
  #pragma unroll
  for (int rep = 0; rep < 2; rep++) {
    int u = threadIdx.x + rep * 256;
    int n = u >> 3, c8 = u & 7;
    s16x8 hv, lv;
    #pragma unroll
    for (int e = 0; e < 8; e++) {
      float v = tile[c8 * 8 + e][n];    // = W[k0+c8*8+e][n0+n]
      if (wi == 3) {
        hv[e] = (short)__builtin_bit_cast(u16, (_Float16)v);
      } else {
        u16 hb = f2bf(v);
        hv[e] = (short)hb;
        lv[e] = (short)f2bf(v - bf2f(hb));
      }
    }
    size_t oi = obase + (size_t)(n0 + n) * DIMM + k0 + c8 * 8;
    *(s16x8*)&WTh[oi] = hv;
    if (wi != 3) *(s16x8*)&WTl[oi] = lv;
  }
}

// ---------------- fused QKV GEMM: 128x128 tile, 8 waves, 64 KB LDS --------
// XCD-aware nt-major swizzle: 1-D grid 576 = 8 XCDs x 72; each XCD owns
// ~4.5 consecutive B-panels x all 16 m-blocks -> B panel L2-resident, so
// the per-K-step vmcnt(0) drain sees L2-hit (~200cy) not HBM (~900cy).
__global__ __launch_bounds__(512, 4) void gemm3_k(const u16* __restrict__ Ahp,
                                                  const u16* __restrict__ Alp,
                                                  const u16* __restrict__ WTh,
                                                  const u16* __restrict__ WTl,
                                                  const float* __restrict__ bq,
                                                  const float* __restrict__ bk,
                                                  const float* __restrict__ bv,
                                                  float* __restrict__ C,
                                                  u16* __restrict__ vbfT) {
  __shared__ u16 As[2][128][64];   // [hi/lo][row][k-chunk-swizzled]  32 KB
  __shared__ u16 Bs[2][128][64];   //                                32 KB
  const int tid = threadIdx.x;
  const int w = tid >> 6, lane = tid & 63, quad = lane >> 4, l16 = lane & 15;
  const int wr = w >> 2, wc = w & 3;         // 2 row-halves x 4 col-quarters
  const int bid = blockIdx.x;
  const int swz = (bid & 7) * 72 + (bid >> 3);   // bijective: 576 = 8*72
  const int nt = swz >> 4;                   // 0..35 (nt-major per XCD)
  const int mi = swz & 15;
  const int m_base = mi * 128;
  const int wi = nt / 12;
  const int n_in = (nt % 12) * 128;
  const u16* Bh0 = WTh + ((size_t)wi * DIMM + n_in) * DIMM;
  const u16* Bl0 = WTl + ((size_t)wi * DIMM + n_in) * DIMM;
  const float* bias = (wi == 0) ? bq : (wi == 1) ? bk : bv;
  const bool split = (wi != 2);              // V = single-pass

  const int srow = lane >> 3;                          // 0..7
  const int skc = (((lane & 7) ^ srow) * 8);           // swizzled global col (u16)
  const int rx = (l16 & 7);                            // read-side xor term

  f32x4 zero4 = {0.f, 0.f, 0.f, 0.f};
  f32x4 acc[4][2];                 // rows wr*64+i*16, cols wc*32+j*16
  #pragma unroll
  for (int i = 0; i < 4; i++)
    #pragma unroll
    for (int j = 0; j < 2; j++) acc[i][j] = zero4;

  for (int k0 = 0; k0 < DIMM; k0 += 64) {
    #pragma unroll
    for (int c = 0; c < 2; c++) {
      int r0 = w * 16 + c * 8;
      int row = r0 + srow;
      dma16(&Ahp[(size_t)(m_base + row) * DIMM + k0 + skc], &As[0][r0][0]);
      dma16(&Bh0[(size_t)row * DIMM + k0 + skc], &Bs[0][r0][0]);
      if (split) {
        dma16(&Alp[(size_t)(m_base + row) * DIMM + k0 + skc], &As[1][r0][0]);
        dma16(&Bl0[(size_t)row * DIMM + k0 + skc], &Bs[1][r0][0]);
      }
    }
    __syncthreads();
    #pragma unroll
    for (int kk = 0; kk < 2; kk++) {
      const int coff = ((kk * 4 + quad) ^ rx) * 8;     // swizzled read col (u16)
      bf16x8 afh[4], afl[4], bfh[2], bfl[2];
      #pragma unroll
      for (int i = 0; i < 4; i++)
        afh[i] = __builtin_bit_cast(bf16x8,
                 *(const s16x8*)&As[0][wr * 64 + i * 16 + l16][coff]);
      #pragma unroll
      for (int j = 0; j < 2; j++)
        bfh[j] = __builtin_bit_cast(bf16x8,
                 *(const s16x8*)&Bs[0][wc * 32 + j * 16 + l16][coff]);
      if (split) {
        #pragma unroll
        for (int i = 0; i < 4; i++)
          afl[i] = __builtin_bit_cast(bf16x8,
                   *(const s16x8*)&As[1][wr * 64 + i * 16 + l16][coff]);
        #pragma unroll
        for (int j = 0; j < 2; j++)
          bfl[j] = __builtin_bit_cast(bf16x8,
                   *(const s16x8*)&Bs[1][wc * 32 + j * 16 + l16][coff]);
      }
      #pragma unroll
      for (int i = 0; i < 4; i++)
        #pragma unroll
        for (int j = 0; j < 2; j++) {
          acc[i][j] = __builtin_amdgcn_mfma_f32_16x16x32_bf16(afh[i], bfh[j], acc[i][j], 0, 0, 0);
          if (split) {
            acc[i][j] = __builtin_amdgcn_mfma_f32_16x16x32_bf16(afh[i], bfl[j], acc[i][j], 0, 0, 0);
            acc[i][j] = __builtin_amdgcn_mfma_f32_16x16x32_bf16(afl[i], bfh[j], acc[i][j], 0, 0, 0);
          }
        }
    }
    __syncthreads();
  }

  if (wi != 2) {
    #pragma unroll
    for (int i = 0; i < 4; i++)
      #pragma unroll
      for (int j = 0; j < 2; j++) {
        int tc = wc * 32 + j * 16 + l16;
        float bv2 = bias[n_in + tc];
        #pragma unroll
        for (int rg = 0; rg < 4; rg++) {
          int r = m_base + wr * 64 + i * 16 + quad * 4 + rg;
          C[(size_t)r * QS + nt * 128 + tc] = acc[i][j][rg] + bv2;
        }
      }
  } else {
    // V: emit swizzled bf16 vbfT[h][b][d][key] directly.
    int hh = nt % 12;                         // head (N-tile == one head)
    int bblk = mi * 2 + wr;                   // key-block
    u16* vb = vbfT + (size_t)(hh * NKB + bblk) * 8192;
    int kb8 = quad >> 1;
    int klo = (quad & 1) * 4;
    #pragma unroll
    for (int i = 0; i < 4; i++) {
      int k8 = (i * 2 + kb8);                 // key>>3 in [0,8)
      #pragma unroll
      for (int j = 0; j < 2; j++) {
        int d = wc * 32 + j * 16 + l16;       // V column within head
        float bv2 = bias[n_in + d];
        u16x4 o;
        #pragma unroll
        for (int rg = 0; rg < 4; rg++) o[rg] = f2bf(acc[i][j][rg] + bv2);
        *(u16x4*)&vb[d * 64 + ((k8 ^ (d & 7)) << 3) + klo] = o;
      }
    }
  }
}

// ---------------- O GEMM: single-pass f16, 64x128, BK=64, XCD swizzle -----
__global__ __launch_bounds__(256) void gemm_o(const u16* __restrict__ Ap,
                                              const u16* __restrict__ Bp,
                                              const float* __restrict__ bias,
                                              float* __restrict__ C) {
  __shared__ u16 As[64][64];
  __shared__ u16 Bs[128][64];
  const int tid = threadIdx.x;
  const int w = tid >> 6, lane = tid & 63, quad = lane >> 4, l16 = lane & 15;
  const int wr = w >> 1, wc = w & 1;
  const int bid = blockIdx.x;
  const int swz = (bid & 7) * 48 + (bid >> 3);   // bijective: 384 = 8*48
  const int m_base = (swz & 31) * 64, n_base = (swz >> 5) * 128;
  const int srow = lane >> 3;
  const int skc = (((lane & 7) ^ srow) * 8);
  const int rx = (l16 & 7);

  f32x4 zero4 = {0.f, 0.f, 0.f, 0.f};
  f32x4 acc[2][4];
  #pragma unroll
  for (int i = 0; i < 2; i++)
    #pragma unroll
    for (int j = 0; j < 4; j++) acc[i][j] = zero4;

  for (int k0 = 0; k0 < DIMM; k0 += 64) {
    #pragma unroll
    for (int c = 0; c < 2; c++) {
      int r0 = w * 16 + c * 8;
      int row = r0 + srow;
      dma16(&Ap[(size_t)(m_base + row) * DIMM + k0 + skc], &As[r0][0]);
    }
    #pragma unroll
    for (int c = 0; c < 4; c++) {
      int r0 = w * 32 + c * 8;
      int row = r0 + srow;
      dma16(&Bp[(size_t)(n_base + row) * DIMM + k0 + skc], &Bs[r0][0]);
    }
    __syncthreads();
    #pragma unroll
    for (int kk = 0; kk < 2; kk++) {
      const int coff = ((kk * 4 + quad) ^ rx) * 8;
      f16x8 af[2], bf[4];
      #pragma unroll
      for (int i = 0; i < 2; i++)
        af[i] = __builtin_bit_cast(f16x8,
                *(const s16x8*)&As[wr * 32 + i * 16 + l16][coff]);
      #pragma unroll
      for (int j = 0; j < 4; j++)
        bf[j] = __builtin_bit_cast(f16x8,
                *(const s16x8*)&Bs[wc * 64 + j * 16 + l16][coff]);
      #pragma unroll
      for (int i = 0; i < 2; i++)
        #pragma unroll
        for (int j = 0; j < 4; j++)
          acc[i][j] = __builtin_amdgcn_mfma_f32_16x16x32_f16(af[i], bf[j], acc[i][j], 0, 0, 0);
    }
    __syncthreads();
  }
  #pragma unroll
  for (int i = 0; i < 2; i++)
    #pragma unroll
    for (int j = 0; j < 4; j++) {
      int c = n_base + wc * 64 + j * 16 + l16;
      float bv2 = bias[c];
      #pragma unroll
      for (int rg = 0; rg < 4; rg++) {
        int r = m_base + wr * 32 + i * 16 + quad * 4 + rg;
        C[(size_t)r * DIMM + c] = acc[i][j][rg] + bv2;
      }
    }
}

// ---------------- RMSNorm + RoPE + fused bf16 pre-swizzled q/k emit -------
__global__ __launch_bounds__(256) void norm_rope_k(float* __restrict__ qkv,
                                                   const float* __restrict__ gq,
                                                   const float* __restrict__ gk,
                                                   const float* __restrict__ fc,
                                                   const float* __restrict__ fs,
                                                   u16* __restrict__ qbf,
                                                   u16* __restrict__ kbf) {
  int s = blockIdx.x;
  float* row = qkv + (size_t)s * QS + (blockIdx.y == 0 ? 0 : DIMM);
  const float* g = (blockIdx.y == 0) ? gq : gk;
  u16* obase = (blockIdx.y == 0) ? qbf : kbf;
  int t = threadIdx.x;
  float ss = 0.f;
  #pragma unroll
  for (int i = 0; i < 6; i++) {
    float v = row[t + i * 256];
    ss += v * v;
  }
  #pragma unroll
  for (int m = 1; m < 64; m <<= 1) ss += __shfl_xor(ss, m, 64);
  __shared__ float wsum[4];
  if ((t & 63) == 0) wsum[t >> 6] = ss;
  __syncthreads();
  float tot = wsum[0] + wsum[1] + wsum[2] + wsum[3];
  float sc = rsqrtf(tot / 1536.0f + 1e-6f);
  #pragma unroll
  for (int i = 0; i < 3; i++) {
    int p = t + i * 256;
    int h = p >> 6, ip = p & 63;
    int base = h * 128 + 2 * ip;
    float x1 = row[base] * sc * g[base];
    float x2 = row[base + 1] * sc * g[base + 1];
    float c = fc[(size_t)s * 128 + 2 * ip];
    float sn = fs[(size_t)s * 128 + 2 * ip + 1];
    float ev = x1 * c - x2 * sn;
    float od = x1 * sn + x2 * c;
    row[base]     = ev;
    row[base + 1] = od;
    int gsk = ip >> 2, e = (2 * ip) & 7;
    int cc = (gsk & 8) | ((gsk ^ (s & 7)) & 7);
    u16* ob = obase + ((size_t)h * SQ + s) * 128;
    unsigned int pack = (unsigned int)f2bf(ev) | ((unsigned int)f2bf(od) << 16);
    *(unsigned int*)&ob[cc * 8 + e] = pack;
  }
}

// ---------------- merged: kv (MFMA) + block means -------------------------
__global__ __launch_bounds__(256) void kvmeans_k(const float* __restrict__ qf,
                                                 const float* __restrict__ kf,
                                                 const u16* __restrict__ vbfT,
                                                 float* __restrict__ KV,
                                                 float* __restrict__ slk,
                                                 float* __restrict__ qb,
                                                 float* __restrict__ kb) {
  __shared__ u16 lkT[128 * 72];   // [d][key] plain, padded
  __shared__ u16 vtT[128 * 64];   // [d][key] swizzled copy of vbfT tile
  int h = blockIdx.y, t = threadIdx.x;
  if (blockIdx.x >= NKB) {
    int mx = blockIdx.x - NKB;     // 0..47
    if (t < 128) {
      if (mx < NQB) {
        float a = 0.f;
        for (int r = 0; r < 128; r++) a += qf[(size_t)(mx * 128 + r) * QS + h * DH + t];
        qb[(h * NQB + mx) * DH + t] = a * (1.0f / 128.0f);
      } else {
        int ki = mx - NQB;
        float a = 0.f;
        for (int r = 0; r < 64; r++) a += kf[(size_t)(ki * 64 + r) * QS + h * DH + t];
        kb[(h * NKB + ki) * DH + t] = a * (1.0f / 64.0f);
      }
    }
    return;
  }
  int kbi = blockIdx.x;
  int w = t >> 6, lane = t & 63, quad = lane >> 4, l16 = lane & 15;

  {
    const u16* vsrc = vbfT + ((size_t)(h * NKB + kbi)) * 128 * 64;
    #pragma unroll
    for (int c = 0; c < 4; c++)
      dma16(vsrc + (w * 32 + c * 8) * 64 + lane * 8, &vtT[(w * 32 + c * 8) * 64]);
  }
  {
    int r = t >> 2, q4 = t & 3;
    const float* kr = kf + (size_t)(kbi * 64 + r) * QS + h * DH;
    f32x4 x[8];
    float mx = -3.4e38f;
    #pragma unroll
    for (int i = 0; i < 8; i++) {
      x[i] = *(const f32x4*)&kr[q4 * 32 + i * 4];
      mx = fmaxf(mx, fmaxf(fmaxf(x[i][0], x[i][1]), fmaxf(x[i][2], x[i][3])));
    }
    mx = fmaxf(mx, __shfl_xor(mx, 1, 64));
    mx = fmaxf(mx, __shfl_xor(mx, 2, 64));
    float sum = 0.f;
    #pragma unroll
    for (int i = 0; i < 8; i++)
      #pragma unroll
      for (int e = 0; e < 4; e++) { float v = __expf(x[i][e] - mx); x[i][e] = v; sum += v; }
    sum += __shfl_xor(sum, 1, 64);
    sum += __shfl_xor(sum, 2, 64);
    float inv = 1.0f / sum;
    #pragma unroll
    for (int i = 0; i < 8; i++)
      #pragma unroll
      for (int e = 0; e < 4; e++)
        lkT[(q4 * 32 + i * 4 + e) * 72 + r] = f2bf(x[i][e] * inv);
  }
  __syncthreads();

  f32x4 zero4 = {0.f, 0.f, 0.f, 0.f};
  f32x4 acc[2][8];
  #pragma unroll
  for (int i = 0; i < 2; i++)
    #pragma unroll
    for (int j = 0; j < 8; j++) acc[i][j] = zero4;
  #pragma unroll
  for (int kk = 0; kk < 2; kk++) {
    bf16x8 af[2];
    #pragma unroll
    for (int i = 0; i < 2; i++)
      af[i] = __builtin_bit_cast(bf16x8,
              *(const s16x8*)&lkT[(w * 32 + i * 16 + l16) * 72 + kk * 32 + quad * 8]);
    const int voff = ((kk * 4 + quad) ^ (l16 & 7)) * 8;
    #pragma unroll
    for (int j = 0; j < 8; j++) {
      bf16x8 vb = __builtin_bit_cast(bf16x8, *(const s16x8*)&vtT[(j * 16 + l16) * 64 + voff]);
      #pragma unroll
      for (int i = 0; i < 2; i++)
        acc[i][j] = __builtin_amdgcn_mfma_f32_16x16x32_bf16(af[i], vb, acc[i][j], 0, 0, 0);
    }
  }
  float* out = KV + (size_t)(h * NKB + kbi) * 16384;
  #pragma unroll
  for (int i = 0; i < 2; i++)
    #pragma unroll
    for (int j = 0; j < 8; j++) {
      #pragma unroll
      for (int rg = 0; rg < 4; rg++) {
        int r = w * 32 + i * 16 + quad * 4 + rg;
        int c = j * 16 + l16;
        out[(size_t)r * 128 + c] = acc[i][j][rg];
      }
    }
  if (t < 128) {
    float a = 0.f;
    #pragma unroll
    for (int c8 = 0; c8 < 8; c8++) {
      s16x8 v8 = *(const s16x8*)&lkT[t * 72 + c8 * 8];
      #pragma unroll
      for (int e = 0; e < 8; e++) a += bf2f((u16)v8[e]);
    }
    slk[(h * NKB + kbi) * DH + t] = a;
  }
}

// ---------------- merged: per-head totals + top-7 selection ---------------
__global__ __launch_bounds__(256) void kvtot_topk_k(const float* __restrict__ KV,
                                                    const float* __restrict__ slk,
                                                    const float* __restrict__ qb,
                                                    const float* __restrict__ kb,
                                                    float* __restrict__ KVtot,
                                                    float* __restrict__ sltot,
                                                    int* __restrict__ sel) {
  int h = blockIdx.y, t = threadIdx.x;
  if (blockIdx.x < 64) {
    int e = blockIdx.x * 256 + t;
    float a = 0.f;
    for (int b = 0; b < NKB; b++) a += KV[(size_t)(h * NKB + b) * 16384 + e];
    KVtot[(size_t)h * 16384 + e] = a;
    if (blockIdx.x == 0 && t < 128) {
      float s2 = 0.f;
      for (int b = 0; b < NKB; b++) s2 += slk[(h * NKB + b) * DH + t];
      sltot[h * DH + t] = s2;
    }
    return;
  }
  int qi = blockIdx.x - 64;            // 0..15
  __shared__ float scs[NKB];
  int r = t >> 3, sub = t & 7;         // 32 rows x 8 threads
  const float* qv = qb + (size_t)(h * NQB + qi) * DH;
  const float* kv2 = kb + (size_t)(h * NKB + r) * DH;
  float a = 0.f;
  #pragma unroll
  for (int dd = 0; dd < 16; dd++) a += qv[sub * 16 + dd] * kv2[sub * 16 + dd];
  a += __shfl_xor(a, 1, 64);
  a += __shfl_xor(a, 2, 64);
  a += __shfl_xor(a, 4, 64);
  if (sub == 0) scs[r] = a;
  __syncthreads();
  if (t == 0) {
    unsigned int used = 0;
    for (int it = 0; it < KSEL; it++) {
      float best = -3.4e38f; int bi = 0;
      for (int j = 0; j < NKB; j++)
        if (!((used >> j) & 1) && scs[j] > best) { best = scs[j]; bi = j; }
      used |= 1u << bi;
      sel[(h * NQB + qi) * 8 + it] = bi;
    }
  }
}

// ---------------- MT precompute: (KVtot - sum_sel KV)^T, bf16 swizzled ----
__global__ __launch_bounds__(256) void mt_k(const int* __restrict__ sel,
                                            const float* __restrict__ KV,
                                            const float* __restrict__ KVtot,
                                            u16* __restrict__ MTg) {
  __shared__ u16 MT[128 * 136];
  __shared__ int selsh[KSEL];
  int h = blockIdx.y, q2 = blockIdx.x, tid = threadIdx.x;
  if (tid < KSEL) selsh[tid] = sel[(h * NQB + q2) * 8 + tid];
  __syncthreads();
  for (int i = 0; i < 16; i++) {
    int idx = i * 256 + tid;
    int e4 = idx * 4;
    int d1 = e4 >> 7, d2 = e4 & 127;
    f32x4 a = *(const f32x4*)&KVtot[(size_t)h * 16384 + e4];
    #pragma unroll
    for (int k2 = 0; k2 < KSEL; k2++) {
      f32x4 s4 = *(const f32x4*)&KV[(size_t)(h * NKB + selsh[k2]) * 16384 + e4];
      a -= s4;
    }
    #pragma unroll
    for (int j = 0; j < 4; j++) MT[(d2 + j) * 136 + d1] = f2bf(a[j]);
  }
  __syncthreads();
  u16* out = MTg + (size_t)(h * NQB + q2) * 16384;
  #pragma unroll
  for (int i = 0; i < 8; i++) {
    int u = i * 256 + tid;
    int r = u >> 4, kc = u & 15;
    int sc = (kc & 8) | ((kc ^ (r & 7)) & 7);
    *(s16x8*)&out[r * 128 + sc * 8] = *(const s16x8*)&MT[r * 136 + kc * 8];
  }
}

// ---------------- fused sparse attention + linear fallback ----------------
// (round-3 layout restored: 51.2 KB LDS -> 3 blocks/CU; occupancy beats
//  barrier count at this size, per round-4 A/B.)
__global__ __launch_bounds__(256) void attn_k(const u16* __restrict__ qbf,
                                              const u16* __restrict__ kbf,
                                              const u16* __restrict__ vbfT,
                                              const int* __restrict__ sel,
                                              const float* __restrict__ slk,
                                              const float* __restrict__ sltot,
                                              const u16* __restrict__ MTg,
                                              u16* __restrict__ of16) {
  __shared__ u16 smem[25600];
  __shared__ float mrow[64], lrow[64], dent[64], slsh[128];
  __shared__ int selsh[KSEL];
  u16* qt  = smem;             // [64][128]
  u16* vtT = smem + 8192;      // [128][64]
  u16* kt  = smem + 16384;     // [64][128]
  u16* ptb = smem + 16384;     // [64][72]  alias kt
  u16* MT  = smem + 8192;      // [128][128] alias vtT+kt (after bi-loop)

  int h = blockIdx.y, qi = blockIdx.x, tid = threadIdx.x;   // qi: 0..31
  int w = tid >> 6, lane = tid & 63, quad = lane >> 4, l16 = lane & 15;

  {
    const u16* qsrc = qbf + ((size_t)h * SQ + qi * 64) * 128;
    #pragma unroll
    for (int c = 0; c < 4; c++)
      dma16(qsrc + (w * 16 + c * 4) * 128 + lane * 8, &qt[(w * 16 + c * 4) * 128]);
  }
  if (tid < KSEL) selsh[tid] = sel[(h * NQB + (qi >> 1)) * 8 + tid];
  __syncthreads();

  float m_run[4], l_run[4];
  f32x4 zero4 = {0.f, 0.f, 0.f, 0.f};
  f32x4 oacc[8];
  #pragma unroll
  for (int rg = 0; rg < 4; rg++) { m_run[rg] = -3.0e38f; l_run[rg] = 0.f; }
  #pragma unroll
  for (int nt = 0; nt < 8; nt++) oacc[nt] = zero4;

  for (int bi = 0; bi < KSEL; bi++) {
    int b = selsh[bi];
    {
      const u16* ksrc = kbf + ((size_t)h * SQ + b * 64) * 128;
      #pragma unroll
      for (int c = 0; c < 4; c++)
        dma16(ksrc + (w * 16 + c * 4) * 128 + lane * 8, &kt[(w * 16 + c * 4) * 128]);
      const u16* vsrc = vbfT + ((size_t)(h * NKB + b)) * 128 * 64;
      #pragma unroll
      for (int c = 0; c < 4; c++)
        dma16(vsrc + (w * 32 + c * 8) * 64 + lane * 8, &vtT[(w * 32 + c * 8) * 64]);
    }
    __syncthreads();

    // --- QK^T ---
    f32x4 sacc[4];
    #pragma unroll
    for (int nt = 0; nt < 4; nt++) sacc[nt] = zero4;
    __builtin_amdgcn_s_setprio(1);
    #pragma unroll
    for (int kk = 0; kk < 4; kk++) {
      const int kkq = kk * 4 + quad;
      const int qoff = ((kkq & 8) | ((kkq ^ (l16 & 7)) & 7)) * 8;
      bf16x8 af = __builtin_bit_cast(bf16x8, *(const s16x8*)&qt[(w * 16 + l16) * 128 + qoff]);
      #pragma unroll
      for (int nt = 0; nt < 4; nt++) {
        bf16x8 bfr = __builtin_bit_cast(bf16x8, *(const s16x8*)&kt[(nt * 16 + l16) * 128 + qoff]);
        sacc[nt] = __builtin_amdgcn_mfma_f32_16x16x32_bf16(af, bfr, sacc[nt], 0, 0, 0);
      }
    }
    __builtin_amdgcn_s_setprio(0);
    const float SCALE = 0.08838834764831845f;
    #pragma unroll
    for (int nt = 0; nt < 4; nt++) sacc[nt] *= SCALE;

    // --- online softmax ---
    #pragma unroll
    for (int rg = 0; rg < 4; rg++) {
      float bmax = fmaxf(fmaxf(sacc[0][rg], sacc[1][rg]),
                         fmaxf(sacc[2][rg], sacc[3][rg]));
      bmax = fmaxf(bmax, __shfl_xor(bmax, 1, 64));
      bmax = fmaxf(bmax, __shfl_xor(bmax, 2, 64));
      bmax = fmaxf(bmax, __shfl_xor(bmax, 4, 64));
      bmax = fmaxf(bmax, __shfl_xor(bmax, 8, 64));
      float mold = m_run[rg];
      float mnew = fmaxf(mold, bmax);
      float alpha = __expf(mold - mnew);
      float rs = 0.f;
      #pragma unroll
      for (int nt = 0; nt < 4; nt++) {
        float p = __expf(sacc[nt][rg] - mnew);
        sacc[nt][rg] = p; rs += p;
      }
      rs += __shfl_xor(rs, 1, 64);
      rs += __shfl_xor(rs, 2, 64);
      rs += __shfl_xor(rs, 4, 64);
      rs += __shfl_xor(rs, 8, 64);
      m_run[rg] = mnew;
      l_run[rg] = l_run[rg] * alpha + rs;
      #pragma unroll
      for (int nt = 0; nt < 8; nt++) oacc[nt][rg] *= alpha;
    }
    // ptb aliases kt: all waves must be done reading kt before P-store
    __syncthreads();
    #pragma unroll
    for (int rg = 0; rg < 4; rg++) {
      int r = w * 16 + quad * 4 + rg;
      #pragma unroll
      for (int nt = 0; nt < 4; nt++) ptb[r * 72 + nt * 16 + l16] = f2bf(sacc[nt][rg]);
    }
    __syncthreads();

    // --- P @ V^T ---
    __builtin_amdgcn_s_setprio(1);
    #pragma unroll
    for (int kk = 0; kk < 2; kk++) {
      bf16x8 pa = __builtin_bit_cast(bf16x8, *(const s16x8*)&ptb[(w * 16 + l16) * 72 + kk * 32 + quad * 8]);
      #pragma unroll
      for (int nt = 0; nt < 8; nt++) {
        const int voff = ((kk * 4 + quad) ^ (l16 & 7)) * 8;
        bf16x8 vb = __builtin_bit_cast(bf16x8, *(const s16x8*)&vtT[(nt * 16 + l16) * 64 + voff]);
        oacc[nt] = __builtin_amdgcn_mfma_f32_16x16x32_bf16(pa, vb, oacc[nt], 0, 0, 0);
      }
    }
    __builtin_amdgcn_s_setprio(0);
    __syncthreads();
  }

  // MT: straight DMA of precomputed swizzled tile (aliases vtT+kt, now dead)
  {
    const u16* mtb = MTg + (size_t)(h * NQB + (qi >> 1)) * 16384;
    #pragma unroll
    for (int c = 0; c < 8; c++)
      dma16(mtb + (w * 32 + c * 4) * 128 + lane * 8, &MT[(w * 32 + c * 4) * 128]);
  }
  if (l16 == 0) {
    #pragma unroll
    for (int rg = 0; rg < 4; rg++) {
      int r = w * 16 + quad * 4 + rg;
      mrow[r] = m_run[rg];
      lrow[r] = l_run[rg];
    }
  }
  if (tid < 128) {
    float a = sltot[h * DH + tid];
    #pragma unroll
    for (int i = 0; i < KSEL; i++) a -= slk[(h * NKB + selsh[i]) * DH + tid];
    slsh[tid] = a;
  }
  __syncthreads();

  // lq = softmax(q row) * exp(-m): 4 threads per row; exp cached in regs
  {
    int r = tid >> 2, sub = tid & 3;
    float w_r = __expf(-mrow[r]);
    float xr[32];
    float mx = -3.4e38f;
    #pragma unroll
    for (int gi = 0; gi < 4; gi++) {
      int gc = sub * 4 + gi;
      int c = (gc & 8) | ((gc ^ (r & 7)) & 7);
      #pragma unroll
      for (int e = 0; e < 8; e++) {
        float v = bf2f(qt[r * 128 + c * 8 + e]);
        xr[gi * 8 + e] = v;
        mx = fmaxf(mx, v);
      }
    }
    mx = fmaxf(mx, __shfl_xor(mx, 1, 64));
    mx = fmaxf(mx, __shfl_xor(mx, 2, 64));
    float sum = 0.f;
    #pragma unroll
    for (int gi = 0; gi < 4; gi++)
      #pragma unroll
      for (int e = 0; e < 8; e++) {
        float v = __expf(xr[gi * 8 + e] - mx);
        xr[gi * 8 + e] = v;
        sum += v;
      }
    sum += __shfl_xor(sum, 1, 64);
    sum += __shfl_xor(sum, 2, 64);
    float sc2 = w_r / sum;
    float dl = 0.f;
    #pragma unroll
    for (int gi = 0; gi < 4; gi++) {
      int gc = sub * 4 + gi;
      int c = (gc & 8) | ((gc ^ (r & 7)) & 7);
      #pragma unroll
      for (int e = 0; e < 8; e++) {
        float lq = xr[gi * 8 + e] * sc2;
        dl += lq * slsh[gc * 8 + e];
        qt[r * 128 + c * 8 + e] = f2bf(lq);
      }
    }
    dl += __shfl_xor(dl, 1, 64);
    dl += __shfl_xor(dl, 2, 64);
    if (sub == 0) dent[r] = lrow[r] + dl;
  }
  __syncthreads();

  __builtin_amdgcn_s_setprio(1);
  #pragma unroll
  for (int kk = 0; kk < 4; kk++) {
    const int kkq = kk * 4 + quad;
    const int qoff = ((kkq & 8) | ((kkq ^ (l16 & 7)) & 7)) * 8;
    bf16x8 af = __builtin_bit_cast(bf16x8, *(const s16x8*)&qt[(w * 16 + l16) * 128 + qoff]);
    #pragma unroll
    for (int nt = 0; nt < 8; nt++) {
      const int kc = kk * 4 + quad;
      const int mo = ((kc & 8) | ((kc ^ (l16 & 7)) & 7)) * 8;
      bf16x8 mb = __builtin_bit_cast(bf16x8, *(const s16x8*)&MT[(nt * 16 + l16) * 128 + mo]);
      oacc[nt] = __builtin_amdgcn_mfma_f32_16x16x32_bf16(af, mb, oacc[nt], 0, 0, 0);
    }
  }
  __builtin_amdgcn_s_setprio(0);

  // epilogue: of = oacc / dent, f16
  #pragma unroll
  for (int rg = 0; rg < 4; rg++) {
    int r = w * 16 + quad * 4 + rg;
    float inv = 1.0f / dent[r];
    #pragma unroll
    for (int nt = 0; nt < 8; nt++) {
      int c = nt * 16 + l16;
      float v = oacc[nt][rg] * inv;
      size_t oi = (size_t)(qi * 64 + r) * DIMM + h * DH + c;
      of16[oi] = __builtin_bit_cast(u16, (_Float16)v);
    }
  }
}

// -------------------------------------------------------------------------
extern "C" void kernel_launch(void* const* d_in, const int* in_sizes, int n_in,
                              void* d_out, int out_size, void* d_ws, size_t ws_size,
                              hipStream_t stream) {
  const float* hs = (const float*)d_in[0];
  const float* fc = (const float*)d_in[1];
  const float* fs = (const float*)d_in[2];
  const float* Wq = (const float*)d_in[3];
  const float* bq = (const float*)d_in[4];
  const float* Wk = (const float*)d_in[5];
  const float* bk = (const float*)d_in[6];
  const float* Wv = (const float*)d_in[7];
  const float* bv = (const float*)d_in[8];
  const float* Wo = (const float*)d_in[9];
  const float* bo = (const float*)d_in[10];
  const float* gq = (const float*)d_in[11];
  const float* gk = (const float*)d_in[12];

  char* p = (char*)d_ws;
  auto alloc = [&](size_t bytes) {
    char* r = p; p += (bytes + 255) & ~(size_t)255; return r;
  };
  u16* WTh = (u16*)alloc((size_t)4 * DIMM * DIMM * 2);
  u16* WTl = (u16*)alloc((size_t)4 * DIMM * DIMM * 2);
  u16* hsh = (u16*)alloc((size_t)SQ * DIMM * 2);   // reused later as of16
  u16* hsl = (u16*)alloc((size_t)SQ * DIMM * 2);   // reused later as MTg
  float* qkv = (float*)alloc((size_t)SQ * QS * 4);
  u16* qbf = (u16*)alloc((size_t)NH * SQ * DH * 2);
  u16* kbf = (u16*)alloc((size_t)NH * SQ * DH * 2);
  u16* vbfT = (u16*)alloc((size_t)NH * NKB * DH * 64 * 2);
  float* qb = (float*)alloc((size_t)NH * NQB * DH * 4);
  float* kb = (float*)alloc((size_t)NH * NKB * DH * 4);
  int* sel = (int*)alloc((size_t)NH * NQB * 8 * 4);
  float* KV = (float*)alloc((size_t)NH * NKB * DH * DH * 4);
  float* slk = (float*)alloc((size_t)NH * NKB * DH * 4);
  float* KVtot = (float*)alloc((size_t)NH * DH * DH * 4);
  float* sltot = (float*)alloc((size_t)NH * DH * 4);

  float* qf = qkv;
  float* kf = qkv + DIMM;

  prep_all<<<1536 + 2304, 256, 0, stream>>>(hs, hsh, hsl, Wq, Wk, Wv, Wo, WTh, WTl);

  gemm3_k<<<576, 512, 0, stream>>>(hsh, hsl, WTh, WTl, bq, bk, bv, qkv, vbfT);

  norm_rope_k<<<dim3(SQ, 2), 256, 0, stream>>>(qkv, gq, gk, fc, fs, qbf, kbf);
  kvmeans_k<<<dim3(NKB + NQB + NKB, NH), 256, 0, stream>>>(qf, kf, vbfT, KV, slk, qb, kb);
  kvtot_topk_k<<<dim3(64 + NQB, NH), 256, 0, stream>>>(KV, slk, qb, kb, KVtot, sltot, sel);

  // hs staging buffers are dead now; reuse hsh as f16 attention output,
  // hsl as precomputed MT buffer.
  u16* of16 = hsh;
  u16* MTg = hsl;
  mt_k<<<dim3(NQB, NH), 256, 0, stream>>>(sel, KV, KVtot, MTg);
  attn_k<<<dim3(2 * NQB, NH), 256, 0, stream>>>(qbf, kbf, vbfT, sel, slk, sltot, MTg, of16);

  const u16* WTo = WTh + (size_t)3 * DIMM * DIMM;   // f16 W_o^T
  gemm_o<<<384, 256, 0, stream>>>(of16, WTo, bo, (float*)d_out);
}

// Round 7
// 308.780 us; speedup vs baseline: 1.0568x; 1.0568x over previous
//
#include <hip/hip_runtime.h>
#include <hip/hip_bf16.h>

#define SQ   2048
#define DIMM 1536
#define QS   4608          // fused qkv row stride
#define NH   12
#define DH   128
#define NQB  16
#define NKB  32
#define KSEL 7

typedef unsigned short u16;
typedef __bf16 bf16x8 __attribute__((ext_vector_type(8)));
typedef _Float16 f16x8 __attribute__((ext_vector_type(8)));
typedef short  s16x8  __attribute__((ext_vector_type(8)));
typedef float  f32x4  __attribute__((ext_vector_type(4)));
typedef u16    u16x4  __attribute__((ext_vector_type(4)));

__device__ __forceinline__ float bf2f(u16 u) {
  unsigned int x = ((unsigned int)u) << 16;
  return __builtin_bit_cast(float, x);
}
__device__ __forceinline__ u16 f2bf(float f) {
  unsigned int x = __builtin_bit_cast(unsigned int, f);
  x += 0x7fffu + ((x >> 16) & 1u);
  return (u16)(x >> 16);
}

typedef __attribute__((address_space(3))) void lds_vt;
typedef const __attribute__((address_space(1))) void g_vt;
__device__ __forceinline__ void dma16(const void* g, void* l) {
  __builtin_amdgcn_global_load_lds((g_vt*)g, (lds_vt*)l, 16, 0, 0);
}

// ---------------- merged prep: hs hi/lo split + W transpose ---------------
__global__ __launch_bounds__(256) void prep_all(const float* __restrict__ hs,
                                                u16* __restrict__ hh,
                                                u16* __restrict__ hl,
                                                const float* __restrict__ W0,
                                                const float* __restrict__ W1,
                                                const float* __restrict__ W2,
                                                const float* __restrict__ W3,
                                                u16* __restrict__ WTh,
                                                u16* __restrict__ WTl) {
  __shared__ float tile[64][65];
  int bx = blockIdx.x;
  if (bx < 1536) {
    size_t i = ((size_t)bx * 256 + threadIdx.x) * 8;
    f32x4 a = *(const f32x4*)&hs[i];
    f32x4 b = *(const f32x4*)&hs[i + 4];
    s16x8 h, l;
    #pragma unroll
    for (int j = 0; j < 4; j++) {
      u16 hj = f2bf(a[j]); h[j] = (short)hj; l[j] = (short)f2bf(a[j] - bf2f(hj));
      u16 hk = f2bf(b[j]); h[4 + j] = (short)hk; l[4 + j] = (short)f2bf(b[j] - bf2f(hk));
    }
    *(s16x8*)&hh[i] = h;
    *(s16x8*)&hl[i] = l;
    return;
  }
  int b2 = bx - 1536;                  // 0..2303
  int wi = b2 / 576;
  int rest = b2 % 576;
  int k0 = (rest / 24) * 64, n0 = (rest % 24) * 64;
  const float* W = (wi == 0) ? W0 : (wi == 1) ? W1 : (wi == 2) ? W2 : W3;
  int x = threadIdx.x & 63, y = threadIdx.x >> 6;   // 64 x 4
  #pragma unroll
  for (int i = 0; i < 16; i++) {
    int k = y + i * 4;
    tile[k][x] = W[(size_t)(k0 + k) * DIMM + n0 + x];
  }
  __syncthreads();
  size_t obase = (size_t)wi * DIMM * DIMM;
  #pragma unroll
  for (int rep = 0; rep < 2; rep++) {
    int u = threadIdx.x + rep * 256;
    int n = u >> 3, c8 = u & 7;
    s16x8 hv, lv;
    #pragma unroll
    for (int e = 0; e < 8; e++) {
      float v = tile[c8 * 8 + e][n];    // = W[k0+c8*8+e][n0+n]
      if (wi == 3) {
        hv[e] = (short)__builtin_bit_cast(u16, (_Float16)v);
      } else {
        u16 hb = f2bf(v);
        hv[e] = (short)hb;
        lv[e] = (short)f2bf(v - bf2f(hb));
      }
    }
    size_t oi = obase + (size_t)(n0 + n) * DIMM + k0 + c8 * 8;
    *(s16x8*)&WTh[oi] = hv;
    if (wi != 3) *(s16x8*)&WTl[oi] = lv;
  }
}

// ---------------- fused QKV GEMM: 128x128 tile, 8 waves, 64 KB LDS --------
// (round-2 proven version: grid (36,16), BK=64 single-buffer, 0 conflicts.
//  Both XCD swizzles and BK=32 dbuf regressed -> this is the plateau config.)
__global__ __launch_bounds__(512, 4) void gemm3_k(const u16* __restrict__ Ahp,
                                                  const u16* __restrict__ Alp,
                                                  const u16* __restrict__ WTh,
                                                  const u16* __restrict__ WTl,
                                                  const float* __restrict__ bq,
                                                  const float* __restrict__ bk,
                                                  const float* __restrict__ bv,
                                                  float* __restrict__ C,
                                                  u16* __restrict__ vbfT) {
  __shared__ u16 As[2][128][64];   // [hi/lo][row][k-chunk-swizzled]  32 KB
  __shared__ u16 Bs[2][128][64];   //                                32 KB
  const int tid = threadIdx.x;
  const int w = tid >> 6, lane = tid & 63, quad = lane >> 4, l16 = lane & 15;
  const int wr = w >> 2, wc = w & 3;         // 2 row-halves x 4 col-quarters
  const int m_base = blockIdx.y * 128;
  const int nt = blockIdx.x;                 // 0..35
  const int wi = nt / 12;
  const int n_in = (nt % 12) * 128;
  const u16* Bh0 = WTh + ((size_t)wi * DIMM + n_in) * DIMM;
  const u16* Bl0 = WTl + ((size_t)wi * DIMM + n_in) * DIMM;
  const float* bias = (wi == 0) ? bq : (wi == 1) ? bk : bv;
  const bool split = (wi != 2);              // V = single-pass

  const int srow = lane >> 3;                          // 0..7
  const int skc = (((lane & 7) ^ srow) * 8);           // swizzled global col (u16)
  const int rx = (l16 & 7);                            // read-side xor term

  f32x4 zero4 = {0.f, 0.f, 0.f, 0.f};
  f32x4 acc[4][2];                 // rows wr*64+i*16, cols wc*32+j*16
  #pragma unroll
  for (int i = 0; i < 4; i++)
    #pragma unroll
    for (int j = 0; j < 2; j++) acc[i][j] = zero4;

  for (int k0 = 0; k0 < DIMM; k0 += 64) {
    #pragma unroll
    for (int c = 0; c < 2; c++) {
      int r0 = w * 16 + c * 8;
      int row = r0 + srow;
      dma16(&Ahp[(size_t)(m_base + row) * DIMM + k0 + skc], &As[0][r0][0]);
      dma16(&Bh0[(size_t)row * DIMM + k0 + skc], &Bs[0][r0][0]);
      if (split) {
        dma16(&Alp[(size_t)(m_base + row) * DIMM + k0 + skc], &As[1][r0][0]);
        dma16(&Bl0[(size_t)row * DIMM + k0 + skc], &Bs[1][r0][0]);
      }
    }
    __syncthreads();
    #pragma unroll
    for (int kk = 0; kk < 2; kk++) {
      const int coff = ((kk * 4 + quad) ^ rx) * 8;     // swizzled read col (u16)
      bf16x8 afh[4], afl[4], bfh[2], bfl[2];
      #pragma unroll
      for (int i = 0; i < 4; i++)
        afh[i] = __builtin_bit_cast(bf16x8,
                 *(const s16x8*)&As[0][wr * 64 + i * 16 + l16][coff]);
      #pragma unroll
      for (int j = 0; j < 2; j++)
        bfh[j] = __builtin_bit_cast(bf16x8,
                 *(const s16x8*)&Bs[0][wc * 32 + j * 16 + l16][coff]);
      if (split) {
        #pragma unroll
        for (int i = 0; i < 4; i++)
          afl[i] = __builtin_bit_cast(bf16x8,
                   *(const s16x8*)&As[1][wr * 64 + i * 16 + l16][coff]);
        #pragma unroll
        for (int j = 0; j < 2; j++)
          bfl[j] = __builtin_bit_cast(bf16x8,
                   *(const s16x8*)&Bs[1][wc * 32 + j * 16 + l16][coff]);
      }
      #pragma unroll
      for (int i = 0; i < 4; i++)
        #pragma unroll
        for (int j = 0; j < 2; j++) {
          acc[i][j] = __builtin_amdgcn_mfma_f32_16x16x32_bf16(afh[i], bfh[j], acc[i][j], 0, 0, 0);
          if (split) {
            acc[i][j] = __builtin_amdgcn_mfma_f32_16x16x32_bf16(afh[i], bfl[j], acc[i][j], 0, 0, 0);
            acc[i][j] = __builtin_amdgcn_mfma_f32_16x16x32_bf16(afl[i], bfh[j], acc[i][j], 0, 0, 0);
          }
        }
    }
    __syncthreads();
  }

  if (wi != 2) {
    #pragma unroll
    for (int i = 0; i < 4; i++)
      #pragma unroll
      for (int j = 0; j < 2; j++) {
        int tc = wc * 32 + j * 16 + l16;
        float bv2 = bias[n_in + tc];
        #pragma unroll
        for (int rg = 0; rg < 4; rg++) {
          int r = m_base + wr * 64 + i * 16 + quad * 4 + rg;
          C[(size_t)r * QS + nt * 128 + tc] = acc[i][j][rg] + bv2;
        }
      }
  } else {
    // V: emit swizzled bf16 vbfT[h][b][d][key] directly.
    int hh = nt % 12;                         // head (N-tile == one head)
    int bblk = blockIdx.y * 2 + wr;           // key-block
    u16* vb = vbfT + (size_t)(hh * NKB + bblk) * 8192;
    int kb8 = quad >> 1;
    int klo = (quad & 1) * 4;
    #pragma unroll
    for (int i = 0; i < 4; i++) {
      int k8 = (i * 2 + kb8);                 // key>>3 in [0,8)
      #pragma unroll
      for (int j = 0; j < 2; j++) {
        int d = wc * 32 + j * 16 + l16;       // V column within head
        float bv2 = bias[n_in + d];
        u16x4 o;
        #pragma unroll
        for (int rg = 0; rg < 4; rg++) o[rg] = f2bf(acc[i][j][rg] + bv2);
        *(u16x4*)&vb[d * 64 + ((k8 ^ (d & 7)) << 3) + klo] = o;
      }
    }
  }
}

// ---------------- O GEMM: single-pass f16, 64x128, BK=64 ------------------
// (round-2 proven version, grid (12,32); XCD swizzle regressed ~6 us.)
__global__ __launch_bounds__(256) void gemm_o(const u16* __restrict__ Ap,
                                              const u16* __restrict__ Bp,
                                              const float* __restrict__ bias,
                                              float* __restrict__ C) {
  __shared__ u16 As[64][64];
  __shared__ u16 Bs[128][64];
  const int tid = threadIdx.x;
  const int w = tid >> 6, lane = tid & 63, quad = lane >> 4, l16 = lane & 15;
  const int wr = w >> 1, wc = w & 1;
  const int m_base = blockIdx.y * 64, n_base = blockIdx.x * 128;
  const int srow = lane >> 3;
  const int skc = (((lane & 7) ^ srow) * 8);
  const int rx = (l16 & 7);

  f32x4 zero4 = {0.f, 0.f, 0.f, 0.f};
  f32x4 acc[2][4];
  #pragma unroll
  for (int i = 0; i < 2; i++)
    #pragma unroll
    for (int j = 0; j < 4; j++) acc[i][j] = zero4;

  for (int k0 = 0; k0 < DIMM; k0 += 64) {
    #pragma unroll
    for (int c = 0; c < 2; c++) {
      int r0 = w * 16 + c * 8;
      int row = r0 + srow;
      dma16(&Ap[(size_t)(m_base + row) * DIMM + k0 + skc], &As[r0][0]);
    }
    #pragma unroll
    for (int c = 0; c < 4; c++) {
      int r0 = w * 32 + c * 8;
      int row = r0 + srow;
      dma16(&Bp[(size_t)(n_base + row) * DIMM + k0 + skc], &Bs[r0][0]);
    }
    __syncthreads();
    #pragma unroll
    for (int kk = 0; kk < 2; kk++) {
      const int coff = ((kk * 4 + quad) ^ rx) * 8;
      f16x8 af[2], bf[4];
      #pragma unroll
      for (int i = 0; i < 2; i++)
        af[i] = __builtin_bit_cast(f16x8,
                *(const s16x8*)&As[wr * 32 + i * 16 + l16][coff]);
      #pragma unroll
      for (int j = 0; j < 4; j++)
        bf[j] = __builtin_bit_cast(f16x8,
                *(const s16x8*)&Bs[wc * 64 + j * 16 + l16][coff]);
      #pragma unroll
      for (int i = 0; i < 2; i++)
        #pragma unroll
        for (int j = 0; j < 4; j++)
          acc[i][j] = __builtin_amdgcn_mfma_f32_16x16x32_f16(af[i], bf[j], acc[i][j], 0, 0, 0);
    }
    __syncthreads();
  }
  #pragma unroll
  for (int i = 0; i < 2; i++)
    #pragma unroll
    for (int j = 0; j < 4; j++) {
      int c = n_base + wc * 64 + j * 16 + l16;
      float bv2 = bias[c];
      #pragma unroll
      for (int rg = 0; rg < 4; rg++) {
        int r = m_base + wr * 32 + i * 16 + quad * 4 + rg;
        C[(size_t)r * DIMM + c] = acc[i][j][rg] + bv2;
      }
    }
}

// ---------------- RMSNorm + RoPE + fused bf16 pre-swizzled q/k emit -------
__global__ __launch_bounds__(256) void norm_rope_k(float* __restrict__ qkv,
                                                   const float* __restrict__ gq,
                                                   const float* __restrict__ gk,
                                                   const float* __restrict__ fc,
                                                   const float* __restrict__ fs,
                                                   u16* __restrict__ qbf,
                                                   u16* __restrict__ kbf) {
  int s = blockIdx.x;
  float* row = qkv + (size_t)s * QS + (blockIdx.y == 0 ? 0 : DIMM);
  const float* g = (blockIdx.y == 0) ? gq : gk;
  u16* obase = (blockIdx.y == 0) ? qbf : kbf;
  int t = threadIdx.x;
  float ss = 0.f;
  #pragma unroll
  for (int i = 0; i < 6; i++) {
    float v = row[t + i * 256];
    ss += v * v;
  }
  #pragma unroll
  for (int m = 1; m < 64; m <<= 1) ss += __shfl_xor(ss, m, 64);
  __shared__ float wsum[4];
  if ((t & 63) == 0) wsum[t >> 6] = ss;
  __syncthreads();
  float tot = wsum[0] + wsum[1] + wsum[2] + wsum[3];
  float sc = rsqrtf(tot / 1536.0f + 1e-6f);
  #pragma unroll
  for (int i = 0; i < 3; i++) {
    int p = t + i * 256;
    int h = p >> 6, ip = p & 63;
    int base = h * 128 + 2 * ip;
    float x1 = row[base] * sc * g[base];
    float x2 = row[base + 1] * sc * g[base + 1];
    float c = fc[(size_t)s * 128 + 2 * ip];
    float sn = fs[(size_t)s * 128 + 2 * ip + 1];
    float ev = x1 * c - x2 * sn;
    float od = x1 * sn + x2 * c;
    row[base]     = ev;
    row[base + 1] = od;
    int gsk = ip >> 2, e = (2 * ip) & 7;
    int cc = (gsk & 8) | ((gsk ^ (s & 7)) & 7);
    u16* ob = obase + ((size_t)h * SQ + s) * 128;
    unsigned int pack = (unsigned int)f2bf(ev) | ((unsigned int)f2bf(od) << 16);
    *(unsigned int*)&ob[cc * 8 + e] = pack;
  }
}

// ---------------- merged: kv (MFMA) + block means -------------------------
__global__ __launch_bounds__(256) void kvmeans_k(const float* __restrict__ qf,
                                                 const float* __restrict__ kf,
                                                 const u16* __restrict__ vbfT,
                                                 float* __restrict__ KV,
                                                 float* __restrict__ slk,
                                                 float* __restrict__ qb,
                                                 float* __restrict__ kb) {
  __shared__ u16 lkT[128 * 72];   // [d][key] plain, padded
  __shared__ u16 vtT[128 * 64];   // [d][key] swizzled copy of vbfT tile
  int h = blockIdx.y, t = threadIdx.x;
  if (blockIdx.x >= NKB) {
    int mx = blockIdx.x - NKB;     // 0..47
    if (t < 128) {
      if (mx < NQB) {
        float a = 0.f;
        for (int r = 0; r < 128; r++) a += qf[(size_t)(mx * 128 + r) * QS + h * DH + t];
        qb[(h * NQB + mx) * DH + t] = a * (1.0f / 128.0f);
      } else {
        int ki = mx - NQB;
        float a = 0.f;
        for (int r = 0; r < 64; r++) a += kf[(size_t)(ki * 64 + r) * QS + h * DH + t];
        kb[(h * NKB + ki) * DH + t] = a * (1.0f / 64.0f);
      }
    }
    return;
  }
  int kbi = blockIdx.x;
  int w = t >> 6, lane = t & 63, quad = lane >> 4, l16 = lane & 15;

  {
    const u16* vsrc = vbfT + ((size_t)(h * NKB + kbi)) * 128 * 64;
    #pragma unroll
    for (int c = 0; c < 4; c++)
      dma16(vsrc + (w * 32 + c * 8) * 64 + lane * 8, &vtT[(w * 32 + c * 8) * 64]);
  }
  {
    int r = t >> 2, q4 = t & 3;
    const float* kr = kf + (size_t)(kbi * 64 + r) * QS + h * DH;
    f32x4 x[8];
    float mx = -3.4e38f;
    #pragma unroll
    for (int i = 0; i < 8; i++) {
      x[i] = *(const f32x4*)&kr[q4 * 32 + i * 4];
      mx = fmaxf(mx, fmaxf(fmaxf(x[i][0], x[i][1]), fmaxf(x[i][2], x[i][3])));
    }
    mx = fmaxf(mx, __shfl_xor(mx, 1, 64));
    mx = fmaxf(mx, __shfl_xor(mx, 2, 64));
    float sum = 0.f;
    #pragma unroll
    for (int i = 0; i < 8; i++)
      #pragma unroll
      for (int e = 0; e < 4; e++) { float v = __expf(x[i][e] - mx); x[i][e] = v; sum += v; }
    sum += __shfl_xor(sum, 1, 64);
    sum += __shfl_xor(sum, 2, 64);
    float inv = 1.0f / sum;
    #pragma unroll
    for (int i = 0; i < 8; i++)
      #pragma unroll
      for (int e = 0; e < 4; e++)
        lkT[(q4 * 32 + i * 4 + e) * 72 + r] = f2bf(x[i][e] * inv);
  }
  __syncthreads();

  f32x4 zero4 = {0.f, 0.f, 0.f, 0.f};
  f32x4 acc[2][8];
  #pragma unroll
  for (int i = 0; i < 2; i++)
    #pragma unroll
    for (int j = 0; j < 8; j++) acc[i][j] = zero4;
  #pragma unroll
  for (int kk = 0; kk < 2; kk++) {
    bf16x8 af[2];
    #pragma unroll
    for (int i = 0; i < 2; i++)
      af[i] = __builtin_bit_cast(bf16x8,
              *(const s16x8*)&lkT[(w * 32 + i * 16 + l16) * 72 + kk * 32 + quad * 8]);
    const int voff = ((kk * 4 + quad) ^ (l16 & 7)) * 8;
    #pragma unroll
    for (int j = 0; j < 8; j++) {
      bf16x8 vb = __builtin_bit_cast(bf16x8, *(const s16x8*)&vtT[(j * 16 + l16) * 64 + voff]);
      #pragma unroll
      for (int i = 0; i < 2; i++)
        acc[i][j] = __builtin_amdgcn_mfma_f32_16x16x32_bf16(af[i], vb, acc[i][j], 0, 0, 0);
    }
  }
  float* out = KV + (size_t)(h * NKB + kbi) * 16384;
  #pragma unroll
  for (int i = 0; i < 2; i++)
    #pragma unroll
    for (int j = 0; j < 8; j++) {
      #pragma unroll
      for (int rg = 0; rg < 4; rg++) {
        int r = w * 32 + i * 16 + quad * 4 + rg;
        int c = j * 16 + l16;
        out[(size_t)r * 128 + c] = acc[i][j][rg];
      }
    }
  if (t < 128) {
    float a = 0.f;
    #pragma unroll
    for (int c8 = 0; c8 < 8; c8++) {
      s16x8 v8 = *(const s16x8*)&lkT[t * 72 + c8 * 8];
      #pragma unroll
      for (int e = 0; e < 8; e++) a += bf2f((u16)v8[e]);
    }
    slk[(h * NKB + kbi) * DH + t] = a;
  }
}

// ---------------- merged: per-head totals + top-7 selection ---------------
__global__ __launch_bounds__(256) void kvtot_topk_k(const float* __restrict__ KV,
                                                    const float* __restrict__ slk,
                                                    const float* __restrict__ qb,
                                                    const float* __restrict__ kb,
                                                    float* __restrict__ KVtot,
                                                    float* __restrict__ sltot,
                                                    int* __restrict__ sel) {
  int h = blockIdx.y, t = threadIdx.x;
  if (blockIdx.x < 64) {
    int e = blockIdx.x * 256 + t;
    float a = 0.f;
    for (int b = 0; b < NKB; b++) a += KV[(size_t)(h * NKB + b) * 16384 + e];
    KVtot[(size_t)h * 16384 + e] = a;
    if (blockIdx.x == 0 && t < 128) {
      float s2 = 0.f;
      for (int b = 0; b < NKB; b++) s2 += slk[(h * NKB + b) * DH + t];
      sltot[h * DH + t] = s2;
    }
    return;
  }
  int qi = blockIdx.x - 64;            // 0..15
  __shared__ float scs[NKB];
  int r = t >> 3, sub = t & 7;         // 32 rows x 8 threads
  const float* qv = qb + (size_t)(h * NQB + qi) * DH;
  const float* kv2 = kb + (size_t)(h * NKB + r) * DH;
  float a = 0.f;
  #pragma unroll
  for (int dd = 0; dd < 16; dd++) a += qv[sub * 16 + dd] * kv2[sub * 16 + dd];
  a += __shfl_xor(a, 1, 64);
  a += __shfl_xor(a, 2, 64);
  a += __shfl_xor(a, 4, 64);
  if (sub == 0) scs[r] = a;
  __syncthreads();
  if (t == 0) {
    unsigned int used = 0;
    for (int it = 0; it < KSEL; it++) {
      float best = -3.4e38f; int bi = 0;
      for (int j = 0; j < NKB; j++)
        if (!((used >> j) & 1) && scs[j] > best) { best = scs[j]; bi = j; }
      used |= 1u << bi;
      sel[(h * NQB + qi) * 8 + it] = bi;
    }
  }
}

// ---------------- MT precompute: (KVtot - sum_sel KV)^T, bf16 swizzled ----
__global__ __launch_bounds__(256) void mt_k(const int* __restrict__ sel,
                                            const float* __restrict__ KV,
                                            const float* __restrict__ KVtot,
                                            u16* __restrict__ MTg) {
  __shared__ u16 MT[128 * 136];
  __shared__ int selsh[KSEL];
  int h = blockIdx.y, q2 = blockIdx.x, tid = threadIdx.x;
  if (tid < KSEL) selsh[tid] = sel[(h * NQB + q2) * 8 + tid];
  __syncthreads();
  for (int i = 0; i < 16; i++) {
    int idx = i * 256 + tid;
    int e4 = idx * 4;
    int d1 = e4 >> 7, d2 = e4 & 127;
    f32x4 a = *(const f32x4*)&KVtot[(size_t)h * 16384 + e4];
    #pragma unroll
    for (int k2 = 0; k2 < KSEL; k2++) {
      f32x4 s4 = *(const f32x4*)&KV[(size_t)(h * NKB + selsh[k2]) * 16384 + e4];
      a -= s4;
    }
    #pragma unroll
    for (int j = 0; j < 4; j++) MT[(d2 + j) * 136 + d1] = f2bf(a[j]);
  }
  __syncthreads();
  u16* out = MTg + (size_t)(h * NQB + q2) * 16384;
  #pragma unroll
  for (int i = 0; i < 8; i++) {
    int u = i * 256 + tid;
    int r = u >> 4, kc = u & 15;
    int sc = (kc & 8) | ((kc ^ (r & 7)) & 7);
    *(s16x8*)&out[r * 128 + sc * 8] = *(const s16x8*)&MT[r * 136 + kc * 8];
  }
}

// ---------------- fused sparse attention + linear fallback ----------------
__global__ __launch_bounds__(256) void attn_k(const u16* __restrict__ qbf,
                                              const u16* __restrict__ kbf,
                                              const u16* __restrict__ vbfT,
                                              const int* __restrict__ sel,
                                              const float* __restrict__ slk,
                                              const float* __restrict__ sltot,
                                              const u16* __restrict__ MTg,
                                              u16* __restrict__ of16) {
  __shared__ u16 smem[25600];
  __shared__ float mrow[64], lrow[64], dent[64], slsh[128];
  __shared__ int selsh[KSEL];
  u16* qt  = smem;             // [64][128]
  u16* vtT = smem + 8192;      // [128][64]
  u16* kt  = smem + 16384;     // [64][128]
  u16* ptb = smem + 16384;     // [64][72]  alias kt
  u16* MT  = smem + 8192;      // [128][128] alias vtT+kt (after bi-loop)

  int h = blockIdx.y, qi = blockIdx.x, tid = threadIdx.x;   // qi: 0..31
  int w = tid >> 6, lane = tid & 63, quad = lane >> 4, l16 = lane & 15;

  {
    const u16* qsrc = qbf + ((size_t)h * SQ + qi * 64) * 128;
    #pragma unroll
    for (int c = 0; c < 4; c++)
      dma16(qsrc + (w * 16 + c * 4) * 128 + lane * 8, &qt[(w * 16 + c * 4) * 128]);
  }
  if (tid < KSEL) selsh[tid] = sel[(h * NQB + (qi >> 1)) * 8 + tid];
  __syncthreads();

  float m_run[4], l_run[4];
  f32x4 zero4 = {0.f, 0.f, 0.f, 0.f};
  f32x4 oacc[8];
  #pragma unroll
  for (int rg = 0; rg < 4; rg++) { m_run[rg] = -3.0e38f; l_run[rg] = 0.f; }
  #pragma unroll
  for (int nt = 0; nt < 8; nt++) oacc[nt] = zero4;

  for (int bi = 0; bi < KSEL; bi++) {
    int b = selsh[bi];
    {
      const u16* ksrc = kbf + ((size_t)h * SQ + b * 64) * 128;
      #pragma unroll
      for (int c = 0; c < 4; c++)
        dma16(ksrc + (w * 16 + c * 4) * 128 + lane * 8, &kt[(w * 16 + c * 4) * 128]);
      const u16* vsrc = vbfT + ((size_t)(h * NKB + b)) * 128 * 64;
      #pragma unroll
      for (int c = 0; c < 4; c++)
        dma16(vsrc + (w * 32 + c * 8) * 64 + lane * 8, &vtT[(w * 32 + c * 8) * 64]);
    }
    __syncthreads();

    // --- QK^T ---
    f32x4 sacc[4];
    #pragma unroll
    for (int nt = 0; nt < 4; nt++) sacc[nt] = zero4;
    __builtin_amdgcn_s_setprio(1);
    #pragma unroll
    for (int kk = 0; kk < 4; kk++) {
      const int kkq = kk * 4 + quad;
      const int qoff = ((kkq & 8) | ((kkq ^ (l16 & 7)) & 7)) * 8;
      bf16x8 af = __builtin_bit_cast(bf16x8, *(const s16x8*)&qt[(w * 16 + l16) * 128 + qoff]);
      #pragma unroll
      for (int nt = 0; nt < 4; nt++) {
        bf16x8 bfr = __builtin_bit_cast(bf16x8, *(const s16x8*)&kt[(nt * 16 + l16) * 128 + qoff]);
        sacc[nt] = __builtin_amdgcn_mfma_f32_16x16x32_bf16(af, bfr, sacc[nt], 0, 0, 0);
      }
    }
    __builtin_amdgcn_s_setprio(0);
    const float SCALE = 0.08838834764831845f;
    #pragma unroll
    for (int nt = 0; nt < 4; nt++) sacc[nt] *= SCALE;

    // --- online softmax ---
    #pragma unroll
    for (int rg = 0; rg < 4; rg++) {
      float bmax = fmaxf(fmaxf(sacc[0][rg], sacc[1][rg]),
                         fmaxf(sacc[2][rg], sacc[3][rg]));
      bmax = fmaxf(bmax, __shfl_xor(bmax, 1, 64));
      bmax = fmaxf(bmax, __shfl_xor(bmax, 2, 64));
      bmax = fmaxf(bmax, __shfl_xor(bmax, 4, 64));
      bmax = fmaxf(bmax, __shfl_xor(bmax, 8, 64));
      float mold = m_run[rg];
      float mnew = fmaxf(mold, bmax);
      float alpha = __expf(mold - mnew);
      float rs = 0.f;
      #pragma unroll
      for (int nt = 0; nt < 4; nt++) {
        float p = __expf(sacc[nt][rg] - mnew);
        sacc[nt][rg] = p; rs += p;
      }
      rs += __shfl_xor(rs, 1, 64);
      rs += __shfl_xor(rs, 2, 64);
      rs += __shfl_xor(rs, 4, 64);
      rs += __shfl_xor(rs, 8, 64);
      m_run[rg] = mnew;
      l_run[rg] = l_run[rg] * alpha + rs;
      #pragma unroll
      for (int nt = 0; nt < 8; nt++) oacc[nt][rg] *= alpha;
    }
    // ptb aliases kt: all waves must be done reading kt before P-store
    __syncthreads();
    #pragma unroll
    for (int rg = 0; rg < 4; rg++) {
      int r = w * 16 + quad * 4 + rg;
      #pragma unroll
      for (int nt = 0; nt < 4; nt++) ptb[r * 72 + nt * 16 + l16] = f2bf(sacc[nt][rg]);
    }
    __syncthreads();

    // --- P @ V^T ---
    __builtin_amdgcn_s_setprio(1);
    #pragma unroll
    for (int kk = 0; kk < 2; kk++) {
      bf16x8 pa = __builtin_bit_cast(bf16x8, *(const s16x8*)&ptb[(w * 16 + l16) * 72 + kk * 32 + quad * 8]);
      #pragma unroll
      for (int nt = 0; nt < 8; nt++) {
        const int voff = ((kk * 4 + quad) ^ (l16 & 7)) * 8;
        bf16x8 vb = __builtin_bit_cast(bf16x8, *(const s16x8*)&vtT[(nt * 16 + l16) * 64 + voff]);
        oacc[nt] = __builtin_amdgcn_mfma_f32_16x16x32_bf16(pa, vb, oacc[nt], 0, 0, 0);
      }
    }
    __builtin_amdgcn_s_setprio(0);
    __syncthreads();
  }

  // MT: straight DMA of precomputed swizzled tile (aliases vtT+kt, now dead)
  {
    const u16* mtb = MTg + (size_t)(h * NQB + (qi >> 1)) * 16384;
    #pragma unroll
    for (int c = 0; c < 8; c++)
      dma16(mtb + (w * 32 + c * 4) * 128 + lane * 8, &MT[(w * 32 + c * 4) * 128]);
  }
  if (l16 == 0) {
    #pragma unroll
    for (int rg = 0; rg < 4; rg++) {
      int r = w * 16 + quad * 4 + rg;
      mrow[r] = m_run[rg];
      lrow[r] = l_run[rg];
    }
  }
  if (tid < 128) {
    float a = sltot[h * DH + tid];
    #pragma unroll
    for (int i = 0; i < KSEL; i++) a -= slk[(h * NKB + selsh[i]) * DH + tid];
    slsh[tid] = a;
  }
  __syncthreads();

  // lq = softmax(q row) * exp(-m): 4 threads per row; exp cached in regs
  {
    int r = tid >> 2, sub = tid & 3;
    float w_r = __expf(-mrow[r]);
    float xr[32];
    float mx = -3.4e38f;
    #pragma unroll
    for (int gi = 0; gi < 4; gi++) {
      int gc = sub * 4 + gi;
      int c = (gc & 8) | ((gc ^ (r & 7)) & 7);
      #pragma unroll
      for (int e = 0; e < 8; e++) {
        float v = bf2f(qt[r * 128 + c * 8 + e]);
        xr[gi * 8 + e] = v;
        mx = fmaxf(mx, v);
      }
    }
    mx = fmaxf(mx, __shfl_xor(mx, 1, 64));
    mx = fmaxf(mx, __shfl_xor(mx, 2, 64));
    float sum = 0.f;
    #pragma unroll
    for (int gi = 0; gi < 4; gi++)
      #pragma unroll
      for (int e = 0; e < 8; e++) {
        float v = __expf(xr[gi * 8 + e] - mx);
        xr[gi * 8 + e] = v;
        sum += v;
      }
    sum += __shfl_xor(sum, 1, 64);
    sum += __shfl_xor(sum, 2, 64);
    float sc2 = w_r / sum;
    float dl = 0.f;
    #pragma unroll
    for (int gi = 0; gi < 4; gi++) {
      int gc = sub * 4 + gi;
      int c = (gc & 8) | ((gc ^ (r & 7)) & 7);
      #pragma unroll
      for (int e = 0; e < 8; e++) {
        float lq = xr[gi * 8 + e] * sc2;
        dl += lq * slsh[gc * 8 + e];
        qt[r * 128 + c * 8 + e] = f2bf(lq);
      }
    }
    dl += __shfl_xor(dl, 1, 64);
    dl += __shfl_xor(dl, 2, 64);
    if (sub == 0) dent[r] = lrow[r] + dl;
  }
  __syncthreads();

  __builtin_amdgcn_s_setprio(1);
  #pragma unroll
  for (int kk = 0; kk < 4; kk++) {
    const int kkq = kk * 4 + quad;
    const int qoff = ((kkq & 8) | ((kkq ^ (l16 & 7)) & 7)) * 8;
    bf16x8 af = __builtin_bit_cast(bf16x8, *(const s16x8*)&qt[(w * 16 + l16) * 128 + qoff]);
    #pragma unroll
    for (int nt = 0; nt < 8; nt++) {
      const int kc = kk * 4 + quad;
      const int mo = ((kc & 8) | ((kc ^ (l16 & 7)) & 7)) * 8;
      bf16x8 mb = __builtin_bit_cast(bf16x8, *(const s16x8*)&MT[(nt * 16 + l16) * 128 + mo]);
      oacc[nt] = __builtin_amdgcn_mfma_f32_16x16x32_bf16(af, mb, oacc[nt], 0, 0, 0);
    }
  }
  __builtin_amdgcn_s_setprio(0);

  // epilogue: of = oacc / dent, f16
  #pragma unroll
  for (int rg = 0; rg < 4; rg++) {
    int r = w * 16 + quad * 4 + rg;
    float inv = 1.0f / dent[r];
    #pragma unroll
    for (int nt = 0; nt < 8; nt++) {
      int c = nt * 16 + l16;
      float v = oacc[nt][rg] * inv;
      size_t oi = (size_t)(qi * 64 + r) * DIMM + h * DH + c;
      of16[oi] = __builtin_bit_cast(u16, (_Float16)v);
    }
  }
}

// -------------------------------------------------------------------------
extern "C" void kernel_launch(void* const* d_in, const int* in_sizes, int n_in,
                              void* d_out, int out_size, void* d_ws, size_t ws_size,
                              hipStream_t stream) {
  const float* hs = (const float*)d_in[0];
  const float* fc = (const float*)d_in[1];
  const float* fs = (const float*)d_in[2];
  const float* Wq = (const float*)d_in[3];
  const float* bq = (const float*)d_in[4];
  const float* Wk = (const float*)d_in[5];
  const float* bk = (const float*)d_in[6];
  const float* Wv = (const float*)d_in[7];
  const float* bv = (const float*)d_in[8];
  const float* Wo = (const float*)d_in[9];
  const float* bo = (const float*)d_in[10];
  const float* gq = (const float*)d_in[11];
  const float* gk = (const float*)d_in[12];

  char* p = (char*)d_ws;
  auto alloc = [&](size_t bytes) {
    char* r = p; p += (bytes + 255) & ~(size_t)255; return r;
  };
  u16* WTh = (u16*)alloc((size_t)4 * DIMM * DIMM * 2);
  u16* WTl = (u16*)alloc((size_t)4 * DIMM * DIMM * 2);
  u16* hsh = (u16*)alloc((size_t)SQ * DIMM * 2);   // reused later as of16
  u16* hsl = (u16*)alloc((size_t)SQ * DIMM * 2);   // reused later as MTg
  float* qkv = (float*)alloc((size_t)SQ * QS * 4);
  u16* qbf = (u16*)alloc((size_t)NH * SQ * DH * 2);
  u16* kbf = (u16*)alloc((size_t)NH * SQ * DH * 2);
  u16* vbfT = (u16*)alloc((size_t)NH * NKB * DH * 64 * 2);
  float* qb = (float*)alloc((size_t)NH * NQB * DH * 4);
  float* kb = (float*)alloc((size_t)NH * NKB * DH * 4);
  int* sel = (int*)alloc((size_t)NH * NQB * 8 * 4);
  float* KV = (float*)alloc((size_t)NH * NKB * DH * DH * 4);
  float* slk = (float*)alloc((size_t)NH * NKB * DH * 4);
  float* KVtot = (float*)alloc((size_t)NH * DH * DH * 4);
  float* sltot = (float*)alloc((size_t)NH * DH * 4);

  float* qf = qkv;
  float* kf = qkv + DIMM;

  prep_all<<<1536 + 2304, 256, 0, stream>>>(hs, hsh, hsl, Wq, Wk, Wv, Wo, WTh, WTl);

  gemm3_k<<<dim3(36, 16), 512, 0, stream>>>(hsh, hsl, WTh, WTl, bq, bk, bv, qkv, vbfT);

  norm_rope_k<<<dim3(SQ, 2), 256, 0, stream>>>(qkv, gq, gk, fc, fs, qbf, kbf);
  kvmeans_k<<<dim3(NKB + NQB + NKB, NH), 256, 0, stream>>>(qf, kf, vbfT, KV, slk, qb, kb);
  kvtot_topk_k<<<dim3(64 + NQB, NH), 256, 0, stream>>>(KV, slk, qb, kb, KVtot, sltot, sel);

  // hs staging buffers are dead now; reuse hsh as f16 attention output,
  // hsl as precomputed MT buffer.
  u16* of16 = hsh;
  u16* MTg = hsl;
  mt_k<<<dim3(NQB, NH), 256, 0, stream>>>(sel, KV, KVtot, MTg);
  attn_k<<<dim3(2 * NQB, NH), 256, 0, stream>>>(qbf, kbf, vbfT, sel, slk, sltot, MTg, of16);

  const u16* WTo = WTh + (size_t)3 * DIMM * DIMM;   // f16 W_o^T
  gemm_o<<<dim3(12, 32), 256, 0, stream>>>(of16, WTo, bo, (float*)d_out);
}

// Round 9
// 300.295 us; speedup vs baseline: 1.0866x; 1.0283x over previous
//
#include <hip/hip_runtime.h>
#include <hip/hip_bf16.h>

#define SQ   2048
#define DIMM 1536
#define QS   4608          // fused qkv row stride
#define NH   12
#define DH   128
#define NQB  16
#define NKB  32
#define KSEL 7

typedef unsigned short u16;
typedef __bf16 bf16x8 __attribute__((ext_vector_type(8)));
typedef _Float16 f16x8 __attribute__((ext_vector_type(8)));
typedef short  s16x8  __attribute__((ext_vector_type(8)));
typedef float  f32x4  __attribute__((ext_vector_type(4)));
typedef u16    u16x4  __attribute__((ext_vector_type(4)));

__device__ __forceinline__ float bf2f(u16 u) {
  unsigned int x = ((unsigned int)u) << 16;
  return __builtin_bit_cast(float, x);
}
__device__ __forceinline__ u16 f2bf(float f) {
  unsigned int x = __builtin_bit_cast(unsigned int, f);
  x += 0x7fffu + ((x >> 16) & 1u);
  return (u16)(x >> 16);
}

typedef __attribute__((address_space(3))) void lds_vt;
typedef const __attribute__((address_space(1))) void g_vt;
__device__ __forceinline__ void dma16(const void* g, void* l) {
  __builtin_amdgcn_global_load_lds((g_vt*)g, (lds_vt*)l, 16, 0, 0);
}

// ---------------- merged prep: hs hi/lo split + W transpose ---------------
__global__ __launch_bounds__(256) void prep_all(const float* __restrict__ hs,
                                                u16* __restrict__ hh,
                                                u16* __restrict__ hl,
                                                const float* __restrict__ W0,
                                                const float* __restrict__ W1,
                                                const float* __restrict__ W2,
                                                const float* __restrict__ W3,
                                                u16* __restrict__ WTh,
                                                u16* __restrict__ WTl) {
  __shared__ float tile[64][65];
  int bx = blockIdx.x;
  if (bx < 1536) {
    size_t i = ((size_t)bx * 256 + threadIdx.x) * 8;
    f32x4 a = *(const f32x4*)&hs[i];
    f32x4 b = *(const f32x4*)&hs[i + 4];
    s16x8 h, l;
    #pragma unroll
    for (int j = 0; j < 4; j++) {
      u16 hj = f2bf(a[j]); h[j] = (short)hj; l[j] = (short)f2bf(a[j] - bf2f(hj));
      u16 hk = f2bf(b[j]); h[4 + j] = (short)hk; l[4 + j] = (short)f2bf(b[j] - bf2f(hk));
    }
    *(s16x8*)&hh[i] = h;
    *(s16x8*)&hl[i] = l;
    return;
  }
  int b2 = bx - 1536;                  // 0..2303
  int wi = b2 / 576;
  int rest = b2 % 576;
  int k0 = (rest / 24) * 64, n0 = (rest % 24) * 64;
  const float* W = (wi == 0) ? W0 : (wi == 1) ? W1 : (wi == 2) ? W2 : W3;
  int x = threadIdx.x & 63, y = threadIdx.x >> 6;   // 64 x 4
  #pragma unroll
  for (int i = 0; i < 16; i++) {
    int k = y + i * 4;
    tile[k][x] = W[(size_t)(k0 + k) * DIMM + n0 + x];
  }
  __syncthreads();
  size_t obase = (size_t)wi * DIMM * DIMM;
  #pragma unroll
  for (int rep = 0; rep < 2; rep++) {
    int u = threadIdx.x + rep * 256;
    int n = u >> 3, c8 = u & 7;
    s16x8 hv, lv;
    #pragma unroll
    for (int e = 0; e < 8; e++) {
      float v = tile[c8 * 8 + e][n];    // = W[k0+c8*8+e][n0+n]
      if (wi == 3) {
        hv[e] = (short)__builtin_bit_cast(u16, (_Float16)v);
      } else {
        u16 hb = f2bf(v);
        hv[e] = (short)hb;
        lv[e] = (short)f2bf(v - bf2f(hb));
      }
    }
    size_t oi = obase + (size_t)(n0 + n) * DIMM + k0 + c8 * 8;
    *(s16x8*)&WTh[oi] = hv;
    if (wi < 2) *(s16x8*)&WTl[oi] = lv;   // V's lo-plane is never read
  }
}

// ---------------- fused QKV GEMM: 128x128 tile, 8 waves, 64 KB LDS --------
// STRUCTURAL PLATEAU (~743 TF): split-precision needs 4 staged planes
// (64 KB/K-step) -> no dbuf within 2-blocks/CU; BK=32 dbuf bank-conflicts
// (R3: 8.8M cyc); XCD swizzle destroys A-panel sharing (R5: -17 us).
__global__ __launch_bounds__(512, 4) void gemm3_k(const u16* __restrict__ Ahp,
                                                  const u16* __restrict__ Alp,
                                                  const u16* __restrict__ WTh,
                                                  const u16* __restrict__ WTl,
                                                  const float* __restrict__ bq,
                                                  const float* __restrict__ bk,
                                                  const float* __restrict__ bv,
                                                  float* __restrict__ C,
                                                  u16* __restrict__ vbfT) {
  __shared__ u16 As[2][128][64];   // [hi/lo][row][k-chunk-swizzled]  32 KB
  __shared__ u16 Bs[2][128][64];   //                                32 KB
  const int tid = threadIdx.x;
  const int w = tid >> 6, lane = tid & 63, quad = lane >> 4, l16 = lane & 15;
  const int wr = w >> 2, wc = w & 3;         // 2 row-halves x 4 col-quarters
  const int m_base = blockIdx.y * 128;
  const int nt = blockIdx.x;                 // 0..35
  const int wi = nt / 12;
  const int n_in = (nt % 12) * 128;
  const u16* Bh0 = WTh + ((size_t)wi * DIMM + n_in) * DIMM;
  const u16* Bl0 = WTl + ((size_t)wi * DIMM + n_in) * DIMM;
  const float* bias = (wi == 0) ? bq : (wi == 1) ? bk : bv;
  const bool split = (wi != 2);              // V = single-pass

  const int srow = lane >> 3;                          // 0..7
  const int skc = (((lane & 7) ^ srow) * 8);           // swizzled global col (u16)
  const int rx = (l16 & 7);                            // read-side xor term

  f32x4 zero4 = {0.f, 0.f, 0.f, 0.f};
  f32x4 acc[4][2];                 // rows wr*64+i*16, cols wc*32+j*16
  #pragma unroll
  for (int i = 0; i < 4; i++)
    #pragma unroll
    for (int j = 0; j < 2; j++) acc[i][j] = zero4;

  for (int k0 = 0; k0 < DIMM; k0 += 64) {
    #pragma unroll
    for (int c = 0; c < 2; c++) {
      int r0 = w * 16 + c * 8;
      int row = r0 + srow;
      dma16(&Ahp[(size_t)(m_base + row) * DIMM + k0 + skc], &As[0][r0][0]);
      dma16(&Bh0[(size_t)row * DIMM + k0 + skc], &Bs[0][r0][0]);
      if (split) {
        dma16(&Alp[(size_t)(m_base + row) * DIMM + k0 + skc], &As[1][r0][0]);
        dma16(&Bl0[(size_t)row * DIMM + k0 + skc], &Bs[1][r0][0]);
      }
    }
    __syncthreads();
    #pragma unroll
    for (int kk = 0; kk < 2; kk++) {
      const int coff = ((kk * 4 + quad) ^ rx) * 8;     // swizzled read col (u16)
      bf16x8 afh[4], afl[4], bfh[2], bfl[2];
      #pragma unroll
      for (int i = 0; i < 4; i++)
        afh[i] = __builtin_bit_cast(bf16x8,
                 *(const s16x8*)&As[0][wr * 64 + i * 16 + l16][coff]);
      #pragma unroll
      for (int j = 0; j < 2; j++)
        bfh[j] = __builtin_bit_cast(bf16x8,
                 *(const s16x8*)&Bs[0][wc * 32 + j * 16 + l16][coff]);
      if (split) {
        #pragma unroll
        for (int i = 0; i < 4; i++)
          afl[i] = __builtin_bit_cast(bf16x8,
                   *(const s16x8*)&As[1][wr * 64 + i * 16 + l16][coff]);
        #pragma unroll
        for (int j = 0; j < 2; j++)
          bfl[j] = __builtin_bit_cast(bf16x8,
                   *(const s16x8*)&Bs[1][wc * 32 + j * 16 + l16][coff]);
      }
      #pragma unroll
      for (int i = 0; i < 4; i++)
        #pragma unroll
        for (int j = 0; j < 2; j++) {
          acc[i][j] = __builtin_amdgcn_mfma_f32_16x16x32_bf16(afh[i], bfh[j], acc[i][j], 0, 0, 0);
          if (split) {
            acc[i][j] = __builtin_amdgcn_mfma_f32_16x16x32_bf16(afh[i], bfl[j], acc[i][j], 0, 0, 0);
            acc[i][j] = __builtin_amdgcn_mfma_f32_16x16x32_bf16(afl[i], bfh[j], acc[i][j], 0, 0, 0);
          }
        }
    }
    __syncthreads();
  }

  if (wi != 2) {
    #pragma unroll
    for (int i = 0; i < 4; i++)
      #pragma unroll
      for (int j = 0; j < 2; j++) {
        int tc = wc * 32 + j * 16 + l16;
        float bv2 = bias[n_in + tc];
        #pragma unroll
        for (int rg = 0; rg < 4; rg++) {
          int r = m_base + wr * 64 + i * 16 + quad * 4 + rg;
          C[(size_t)r * QS + nt * 128 + tc] = acc[i][j][rg] + bv2;
        }
      }
  } else {
    // V: emit swizzled bf16 vbfT[h][b][d][key] directly.
    int hh = nt % 12;                         // head (N-tile == one head)
    int bblk = blockIdx.y * 2 + wr;           // key-block
    u16* vb = vbfT + (size_t)(hh * NKB + bblk) * 8192;
    int kb8 = quad >> 1;
    int klo = (quad & 1) * 4;
    #pragma unroll
    for (int i = 0; i < 4; i++) {
      int k8 = (i * 2 + kb8);                 // key>>3 in [0,8)
      #pragma unroll
      for (int j = 0; j < 2; j++) {
        int d = wc * 32 + j * 16 + l16;       // V column within head
        float bv2 = bias[n_in + d];
        u16x4 o;
        #pragma unroll
        for (int rg = 0; rg < 4; rg++) o[rg] = f2bf(acc[i][j][rg] + bv2);
        *(u16x4*)&vb[d * 64 + ((k8 ^ (d & 7)) << 3) + klo] = o;
      }
    }
  }
}

// ---------------- O GEMM: single-pass f16, 64x128, BK=64 ------------------
__global__ __launch_bounds__(256) void gemm_o(const u16* __restrict__ Ap,
                                              const u16* __restrict__ Bp,
                                              const float* __restrict__ bias,
                                              float* __restrict__ C) {
  __shared__ u16 As[64][64];
  __shared__ u16 Bs[128][64];
  const int tid = threadIdx.x;
  const int w = tid >> 6, lane = tid & 63, quad = lane >> 4, l16 = lane & 15;
  const int wr = w >> 1, wc = w & 1;
  const int m_base = blockIdx.y * 64, n_base = blockIdx.x * 128;
  const int srow = lane >> 3;
  const int skc = (((lane & 7) ^ srow) * 8);
  const int rx = (l16 & 7);

  f32x4 zero4 = {0.f, 0.f, 0.f, 0.f};
  f32x4 acc[2][4];
  #pragma unroll
  for (int i = 0; i < 2; i++)
    #pragma unroll
    for (int j = 0; j < 4; j++) acc[i][j] = zero4;

  for (int k0 = 0; k0 < DIMM; k0 += 64) {
    #pragma unroll
    for (int c = 0; c < 2; c++) {
      int r0 = w * 16 + c * 8;
      int row = r0 + srow;
      dma16(&Ap[(size_t)(m_base + row) * DIMM + k0 + skc], &As[r0][0]);
    }
    #pragma unroll
    for (int c = 0; c < 4; c++) {
      int r0 = w * 32 + c * 8;
      int row = r0 + srow;
      dma16(&Bp[(size_t)(n_base + row) * DIMM + k0 + skc], &Bs[r0][0]);
    }
    __syncthreads();
    #pragma unroll
    for (int kk = 0; kk < 2; kk++) {
      const int coff = ((kk * 4 + quad) ^ rx) * 8;
      f16x8 af[2], bf[4];
      #pragma unroll
      for (int i = 0; i < 2; i++)
        af[i] = __builtin_bit_cast(f16x8,
                *(const s16x8*)&As[wr * 32 + i * 16 + l16][coff]);
      #pragma unroll
      for (int j = 0; j < 4; j++)
        bf[j] = __builtin_bit_cast(f16x8,
                *(const s16x8*)&Bs[wc * 64 + j * 16 + l16][coff]);
      #pragma unroll
      for (int i = 0; i < 2; i++)
        #pragma unroll
        for (int j = 0; j < 4; j++)
          acc[i][j] = __builtin_amdgcn_mfma_f32_16x16x32_f16(af[i], bf[j], acc[i][j], 0, 0, 0);
    }
    __syncthreads();
  }
  #pragma unroll
  for (int i = 0; i < 2; i++)
    #pragma unroll
    for (int j = 0; j < 4; j++) {
      int c = n_base + wc * 64 + j * 16 + l16;
      float bv2 = bias[c];
      #pragma unroll
      for (int rg = 0; rg < 4; rg++) {
        int r = m_base + wr * 32 + i * 16 + quad * 4 + rg;
        C[(size_t)r * DIMM + c] = acc[i][j][rg] + bv2;
      }
    }
}

// ---------------- RMSNorm + RoPE + fused bf16 pre-swizzled q/k emit -------
__global__ __launch_bounds__(256) void norm_rope_k(float* __restrict__ qkv,
                                                   const float* __restrict__ gq,
                                                   const float* __restrict__ gk,
                                                   const float* __restrict__ fc,
                                                   const float* __restrict__ fs,
                                                   u16* __restrict__ qbf,
                                                   u16* __restrict__ kbf) {
  int s = blockIdx.x;
  float* row = qkv + (size_t)s * QS + (blockIdx.y == 0 ? 0 : DIMM);
  const float* g = (blockIdx.y == 0) ? gq : gk;
  u16* obase = (blockIdx.y == 0) ? qbf : kbf;
  int t = threadIdx.x;
  float ss = 0.f;
  #pragma unroll
  for (int i = 0; i < 6; i++) {
    float v = row[t + i * 256];
    ss += v * v;
  }
  #pragma unroll
  for (int m = 1; m < 64; m <<= 1) ss += __shfl_xor(ss, m, 64);
  __shared__ float wsum[4];
  if ((t & 63) == 0) wsum[t >> 6] = ss;
  __syncthreads();
  float tot = wsum[0] + wsum[1] + wsum[2] + wsum[3];
  float sc = rsqrtf(tot / 1536.0f + 1e-6f);
  #pragma unroll
  for (int i = 0; i < 3; i++) {
    int p = t + i * 256;
    int h = p >> 6, ip = p & 63;
    int base = h * 128 + 2 * ip;
    float x1 = row[base] * sc * g[base];
    float x2 = row[base + 1] * sc * g[base + 1];
    float c = fc[(size_t)s * 128 + 2 * ip];
    float sn = fs[(size_t)s * 128 + 2 * ip + 1];
    float ev = x1 * c - x2 * sn;
    float od = x1 * sn + x2 * c;
    row[base]     = ev;
    row[base + 1] = od;
    int gsk = ip >> 2, e = (2 * ip) & 7;
    int cc = (gsk & 8) | ((gsk ^ (s & 7)) & 7);
    u16* ob = obase + ((size_t)h * SQ + s) * 128;
    unsigned int pack = (unsigned int)f2bf(ev) | ((unsigned int)f2bf(od) << 16);
    *(unsigned int*)&ob[cc * 8 + e] = pack;
  }
}

// ---------------- merged: kv (MFMA) + block means -------------------------
__global__ __launch_bounds__(256) void kvmeans_k(const float* __restrict__ qf,
                                                 const float* __restrict__ kf,
                                                 const u16* __restrict__ vbfT,
                                                 float* __restrict__ KV,
                                                 float* __restrict__ slk,
                                                 float* __restrict__ qb,
                                                 float* __restrict__ kb) {
  __shared__ u16 lkT[128 * 72];   // [d][key] plain, padded
  __shared__ u16 vtT[128 * 64];   // [d][key] swizzled copy of vbfT tile
  int h = blockIdx.y, t = threadIdx.x;
  if (blockIdx.x >= NKB) {
    int mx = blockIdx.x - NKB;     // 0..47
    if (t < 128) {
      if (mx < NQB) {
        float a = 0.f;
        for (int r = 0; r < 128; r++) a += qf[(size_t)(mx * 128 + r) * QS + h * DH + t];
        qb[(h * NQB + mx) * DH + t] = a * (1.0f / 128.0f);
      } else {
        int ki = mx - NQB;
        float a = 0.f;
        for (int r = 0; r < 64; r++) a += kf[(size_t)(ki * 64 + r) * QS + h * DH + t];
        kb[(h * NKB + ki) * DH + t] = a * (1.0f / 64.0f);
      }
    }
    return;
  }
  int kbi = blockIdx.x;
  int w = t >> 6, lane = t & 63, quad = lane >> 4, l16 = lane & 15;

  {
    const u16* vsrc = vbfT + ((size_t)(h * NKB + kbi)) * 128 * 64;
    #pragma unroll
    for (int c = 0; c < 4; c++)
      dma16(vsrc + (w * 32 + c * 8) * 64 + lane * 8, &vtT[(w * 32 + c * 8) * 64]);
  }
  {
    int r = t >> 2, q4 = t & 3;
    const float* kr = kf + (size_t)(kbi * 64 + r) * QS + h * DH;
    f32x4 x[8];
    float mx = -3.4e38f;
    #pragma unroll
    for (int i = 0; i < 8; i++) {
      x[i] = *(const f32x4*)&kr[q4 * 32 + i * 4];
      mx = fmaxf(mx, fmaxf(fmaxf(x[i][0], x[i][1]), fmaxf(x[i][2], x[i][3])));
    }
    mx = fmaxf(mx, __shfl_xor(mx, 1, 64));
    mx = fmaxf(mx, __shfl_xor(mx, 2, 64));
    float sum = 0.f;
    #pragma unroll
    for (int i = 0; i < 8; i++)
      #pragma unroll
      for (int e = 0; e < 4; e++) { float v = __expf(x[i][e] - mx); x[i][e] = v; sum += v; }
    sum += __shfl_xor(sum, 1, 64);
    sum += __shfl_xor(sum, 2, 64);
    float inv = 1.0f / sum;
    #pragma unroll
    for (int i = 0; i < 8; i++)
      #pragma unroll
      for (int e = 0; e < 4; e++)
        lkT[(q4 * 32 + i * 4 + e) * 72 + r] = f2bf(x[i][e] * inv);
  }
  __syncthreads();

  f32x4 zero4 = {0.f, 0.f, 0.f, 0.f};
  f32x4 acc[2][8];
  #pragma unroll
  for (int i = 0; i < 2; i++)
    #pragma unroll
    for (int j = 0; j < 8; j++) acc[i][j] = zero4;
  #pragma unroll
  for (int kk = 0; kk < 2; kk++) {
    bf16x8 af[2];
    #pragma unroll
    for (int i = 0; i < 2; i++)
      af[i] = __builtin_bit_cast(bf16x8,
              *(const s16x8*)&lkT[(w * 32 + i * 16 + l16) * 72 + kk * 32 + quad * 8]);
    const int voff = ((kk * 4 + quad) ^ (l16 & 7)) * 8;
    #pragma unroll
    for (int j = 0; j < 8; j++) {
      bf16x8 vb = __builtin_bit_cast(bf16x8, *(const s16x8*)&vtT[(j * 16 + l16) * 64 + voff]);
      #pragma unroll
      for (int i = 0; i < 2; i++)
        acc[i][j] = __builtin_amdgcn_mfma_f32_16x16x32_bf16(af[i], vb, acc[i][j], 0, 0, 0);
    }
  }
  float* out = KV + (size_t)(h * NKB + kbi) * 16384;
  #pragma unroll
  for (int i = 0; i < 2; i++)
    #pragma unroll
    for (int j = 0; j < 8; j++) {
      #pragma unroll
      for (int rg = 0; rg < 4; rg++) {
        int r = w * 32 + i * 16 + quad * 4 + rg;
        int c = j * 16 + l16;
        out[(size_t)r * 128 + c] = acc[i][j][rg];
      }
    }
  if (t < 128) {
    float a = 0.f;
    #pragma unroll
    for (int c8 = 0; c8 < 8; c8++) {
      s16x8 v8 = *(const s16x8*)&lkT[t * 72 + c8 * 8];
      #pragma unroll
      for (int e = 0; e < 8; e++) a += bf2f((u16)v8[e]);
    }
    slk[(h * NKB + kbi) * DH + t] = a;
  }
}

// ---------------- merged: per-head totals + top-7 selection ---------------
__global__ __launch_bounds__(256) void kvtot_topk_k(const float* __restrict__ KV,
                                                    const float* __restrict__ slk,
                                                    const float* __restrict__ qb,
                                                    const float* __restrict__ kb,
                                                    float* __restrict__ KVtot,
                                                    float* __restrict__ sltot,
                                                    int* __restrict__ sel) {
  int h = blockIdx.y, t = threadIdx.x;
  if (blockIdx.x < 64) {
    int e = blockIdx.x * 256 + t;
    float a = 0.f;
    for (int b = 0; b < NKB; b++) a += KV[(size_t)(h * NKB + b) * 16384 + e];
    KVtot[(size_t)h * 16384 + e] = a;
    if (blockIdx.x == 0 && t < 128) {
      float s2 = 0.f;
      for (int b = 0; b < NKB; b++) s2 += slk[(h * NKB + b) * DH + t];
      sltot[h * DH + t] = s2;
    }
    return;
  }
  int qi = blockIdx.x - 64;            // 0..15
  __shared__ float scs[NKB];
  int r = t >> 3, sub = t & 7;         // 32 rows x 8 threads
  const float* qv = qb + (size_t)(h * NQB + qi) * DH;
  const float* kv2 = kb + (size_t)(h * NKB + r) * DH;
  float a = 0.f;
  #pragma unroll
  for (int dd = 0; dd < 16; dd++) a += qv[sub * 16 + dd] * kv2[sub * 16 + dd];
  a += __shfl_xor(a, 1, 64);
  a += __shfl_xor(a, 2, 64);
  a += __shfl_xor(a, 4, 64);
  if (sub == 0) scs[r] = a;
  __syncthreads();
  if (t == 0) {
    unsigned int used = 0;
    for (int it = 0; it < KSEL; it++) {
      float best = -3.4e38f; int bi = 0;
      for (int j = 0; j < NKB; j++)
        if (!((used >> j) & 1) && scs[j] > best) { best = scs[j]; bi = j; }
      used |= 1u << bi;
      sel[(h * NQB + qi) * 8 + it] = bi;
    }
  }
}

// ---------------- MT precompute: (KVtot - sum_sel KV)^T, bf16 swizzled ----
// 1-D grid 192 = 8 XCDs x 24 consecutive units (1.5 heads/XCD): the 7x64KB
// KV slices of a head stay L2-resident across its 16 blocks.
__global__ __launch_bounds__(256) void mt_k(const int* __restrict__ sel,
                                            const float* __restrict__ KV,
                                            const float* __restrict__ KVtot,
                                            u16* __restrict__ MTg) {
  __shared__ u16 MT[128 * 136];
  __shared__ int selsh[KSEL];
  int u0 = (blockIdx.x & 7) * 24 + (blockIdx.x >> 3);   // bijective: 192=8*24
  int h = u0 >> 4, q2 = u0 & 15;
  int tid = threadIdx.x;
  if (tid < KSEL) selsh[tid] = sel[(h * NQB + q2) * 8 + tid];
  __syncthreads();
  for (int i = 0; i < 16; i++) {
    int idx = i * 256 + tid;
    int e4 = idx * 4;
    int d1 = e4 >> 7, d2 = e4 & 127;
    f32x4 a = *(const f32x4*)&KVtot[(size_t)h * 16384 + e4];
    #pragma unroll
    for (int k2 = 0; k2 < KSEL; k2++) {
      f32x4 s4 = *(const f32x4*)&KV[(size_t)(h * NKB + selsh[k2]) * 16384 + e4];
      a -= s4;
    }
    #pragma unroll
    for (int j = 0; j < 4; j++) MT[(d2 + j) * 136 + d1] = f2bf(a[j]);
  }
  __syncthreads();
  u16* out = MTg + (size_t)(h * NQB + q2) * 16384;
  #pragma unroll
  for (int i = 0; i < 8; i++) {
    int u = i * 256 + tid;
    int r = u >> 4, kc = u & 15;
    int sc = (kc & 8) | ((kc ^ (r & 7)) & 7);
    *(s16x8*)&out[r * 128 + sc * 8] = *(const s16x8*)&MT[r * 136 + kc * 8];
  }
}

// ---------------- fused sparse attention + linear fallback ----------------
// 1-D grid 384 = 8 XCDs x 48 consecutive (h,qi) units (1.5 heads/XCD):
// kbf/vbfT per head (~1 MB) become L2-resident across that head's 32
// blocks. Unlike the GEMM swizzles (R5/R6 regressions), attn has no
// competing A-panel reuse -- Q is private per block.
__global__ __launch_bounds__(256) void attn_k(const u16* __restrict__ qbf,
                                              const u16* __restrict__ kbf,
                                              const u16* __restrict__ vbfT,
                                              const int* __restrict__ sel,
                                              const float* __restrict__ slk,
                                              const float* __restrict__ sltot,
                                              const u16* __restrict__ MTg,
                                              u16* __restrict__ of16) {
  __shared__ u16 smem[25600];
  __shared__ float mrow[64], lrow[64], dent[64], slsh[128];
  __shared__ int selsh[KSEL];
  u16* qt  = smem;             // [64][128]
  u16* vtT = smem + 8192;      // [128][64]
  u16* kt  = smem + 16384;     // [64][128]
  u16* ptb = smem + 16384;     // [64][72]  alias kt
  u16* MT  = smem + 8192;      // [128][128] alias vtT+kt (after bi-loop)

  int u0 = (blockIdx.x & 7) * 48 + (blockIdx.x >> 3);   // bijective: 384=8*48
  int h = u0 >> 5, qi = u0 & 31;                        // qi: 0..31
  int tid = threadIdx.x;
  int w = tid >> 6, lane = tid & 63, quad = lane >> 4, l16 = lane & 15;

  {
    const u16* qsrc = qbf + ((size_t)h * SQ + qi * 64) * 128;
    #pragma unroll
    for (int c = 0; c < 4; c++)
      dma16(qsrc + (w * 16 + c * 4) * 128 + lane * 8, &qt[(w * 16 + c * 4) * 128]);
  }
  if (tid < KSEL) selsh[tid] = sel[(h * NQB + (qi >> 1)) * 8 + tid];
  __syncthreads();

  float m_run[4], l_run[4];
  f32x4 zero4 = {0.f, 0.f, 0.f, 0.f};
  f32x4 oacc[8];
  #pragma unroll
  for (int rg = 0; rg < 4; rg++) { m_run[rg] = -3.0e38f; l_run[rg] = 0.f; }
  #pragma unroll
  for (int nt = 0; nt < 8; nt++) oacc[nt] = zero4;

  for (int bi = 0; bi < KSEL; bi++) {
    int b = selsh[bi];
    {
      const u16* ksrc = kbf + ((size_t)h * SQ + b * 64) * 128;
      #pragma unroll
      for (int c = 0; c < 4; c++)
        dma16(ksrc + (w * 16 + c * 4) * 128 + lane * 8, &kt[(w * 16 + c * 4) * 128]);
      const u16* vsrc = vbfT + ((size_t)(h * NKB + b)) * 128 * 64;
      #pragma unroll
      for (int c = 0; c < 4; c++)
        dma16(vsrc + (w * 32 + c * 8) * 64 + lane * 8, &vtT[(w * 32 + c * 8) * 64]);
    }
    __syncthreads();

    // --- QK^T ---
    f32x4 sacc[4];
    #pragma unroll
    for (int nt = 0; nt < 4; nt++) sacc[nt] = zero4;
    __builtin_amdgcn_s_setprio(1);
    #pragma unroll
    for (int kk = 0; kk < 4; kk++) {
      const int kkq = kk * 4 + quad;
      const int qoff = ((kkq & 8) | ((kkq ^ (l16 & 7)) & 7)) * 8;
      bf16x8 af = __builtin_bit_cast(bf16x8, *(const s16x8*)&qt[(w * 16 + l16) * 128 + qoff]);
      #pragma unroll
      for (int nt = 0; nt < 4; nt++) {
        bf16x8 bfr = __builtin_bit_cast(bf16x8, *(const s16x8*)&kt[(nt * 16 + l16) * 128 + qoff]);
        sacc[nt] = __builtin_amdgcn_mfma_f32_16x16x32_bf16(af, bfr, sacc[nt], 0, 0, 0);
      }
    }
    __builtin_amdgcn_s_setprio(0);
    const float SCALE = 0.08838834764831845f;
    #pragma unroll
    for (int nt = 0; nt < 4; nt++) sacc[nt] *= SCALE;

    // --- online softmax ---
    #pragma unroll
    for (int rg = 0; rg < 4; rg++) {
      float bmax = fmaxf(fmaxf(sacc[0][rg], sacc[1][rg]),
                         fmaxf(sacc[2][rg], sacc[3][rg]));
      bmax = fmaxf(bmax, __shfl_xor(bmax, 1, 64));
      bmax = fmaxf(bmax, __shfl_xor(bmax, 2, 64));
      bmax = fmaxf(bmax, __shfl_xor(bmax, 4, 64));
      bmax = fmaxf(bmax, __shfl_xor(bmax, 8, 64));
      float mold = m_run[rg];
      float mnew = fmaxf(mold, bmax);
      float alpha = __expf(mold - mnew);
      float rs = 0.f;
      #pragma unroll
      for (int nt = 0; nt < 4; nt++) {
        float p = __expf(sacc[nt][rg] - mnew);
        sacc[nt][rg] = p; rs += p;
      }
      rs += __shfl_xor(rs, 1, 64);
      rs += __shfl_xor(rs, 2, 64);
      rs += __shfl_xor(rs, 4, 64);
      rs += __shfl_xor(rs, 8, 64);
      m_run[rg] = mnew;
      l_run[rg] = l_run[rg] * alpha + rs;
      #pragma unroll
      for (int nt = 0; nt < 8; nt++) oacc[nt][rg] *= alpha;
    }
    // ptb aliases kt: all waves must be done reading kt before P-store
    __syncthreads();
    #pragma unroll
    for (int rg = 0; rg < 4; rg++) {
      int r = w * 16 + quad * 4 + rg;
      #pragma unroll
      for (int nt = 0; nt < 4; nt++) ptb[r * 72 + nt * 16 + l16] = f2bf(sacc[nt][rg]);
    }
    __syncthreads();

    // --- P @ V^T ---
    __builtin_amdgcn_s_setprio(1);
    #pragma unroll
    for (int kk = 0; kk < 2; kk++) {
      bf16x8 pa = __builtin_bit_cast(bf16x8, *(const s16x8*)&ptb[(w * 16 + l16) * 72 + kk * 32 + quad * 8]);
      #pragma unroll
      for (int nt = 0; nt < 8; nt++) {
        const int voff = ((kk * 4 + quad) ^ (l16 & 7)) * 8;
        bf16x8 vb = __builtin_bit_cast(bf16x8, *(const s16x8*)&vtT[(nt * 16 + l16) * 64 + voff]);
        oacc[nt] = __builtin_amdgcn_mfma_f32_16x16x32_bf16(pa, vb, oacc[nt], 0, 0, 0);
      }
    }
    __builtin_amdgcn_s_setprio(0);
    __syncthreads();
  }

  // MT: straight DMA of precomputed swizzled tile (aliases vtT+kt, now dead)
  {
    const u16* mtb = MTg + (size_t)(h * NQB + (qi >> 1)) * 16384;
    #pragma unroll
    for (int c = 0; c < 8; c++)
      dma16(mtb + (w * 32 + c * 4) * 128 + lane * 8, &MT[(w * 32 + c * 4) * 128]);
  }
  if (l16 == 0) {
    #pragma unroll
    for (int rg = 0; rg < 4; rg++) {
      int r = w * 16 + quad * 4 + rg;
      mrow[r] = m_run[rg];
      lrow[r] = l_run[rg];
    }
  }
  if (tid < 128) {
    float a = sltot[h * DH + tid];
    #pragma unroll
    for (int i = 0; i < KSEL; i++) a -= slk[(h * NKB + selsh[i]) * DH + tid];
    slsh[tid] = a;
  }
  __syncthreads();

  // lq = softmax(q row) * exp(-m): 4 threads per row; exp cached in regs
  {
    int r = tid >> 2, sub = tid & 3;
    float w_r = __expf(-mrow[r]);
    float xr[32];
    float mx = -3.4e38f;
    #pragma unroll
    for (int gi = 0; gi < 4; gi++) {
      int gc = sub * 4 + gi;
      int c = (gc & 8) | ((gc ^ (r & 7)) & 7);
      #pragma unroll
      for (int e = 0; e < 8; e++) {
        float v = bf2f(qt[r * 128 + c * 8 + e]);
        xr[gi * 8 + e] = v;
        mx = fmaxf(mx, v);
      }
    }
    mx = fmaxf(mx, __shfl_xor(mx, 1, 64));
    mx = fmaxf(mx, __shfl_xor(mx, 2, 64));
    float sum = 0.f;
    #pragma unroll
    for (int gi = 0; gi < 4; gi++)
      #pragma unroll
      for (int e = 0; e < 8; e++) {
        float v = __expf(xr[gi * 8 + e] - mx);
        xr[gi * 8 + e] = v;
        sum += v;
      }
    sum += __shfl_xor(sum, 1, 64);
    sum += __shfl_xor(sum, 2, 64);
    float sc2 = w_r / sum;
    float dl = 0.f;
    #pragma unroll
    for (int gi = 0; gi < 4; gi++) {
      int gc = sub * 4 + gi;
      int c = (gc & 8) | ((gc ^ (r & 7)) & 7);
      #pragma unroll
      for (int e = 0; e < 8; e++) {
        float lq = xr[gi * 8 + e] * sc2;
        dl += lq * slsh[gc * 8 + e];
        qt[r * 128 + c * 8 + e] = f2bf(lq);
      }
    }
    dl += __shfl_xor(dl, 1, 64);
    dl += __shfl_xor(dl, 2, 64);
    if (sub == 0) dent[r] = lrow[r] + dl;
  }
  __syncthreads();

  __builtin_amdgcn_s_setprio(1);
  #pragma unroll
  for (int kk = 0; kk < 4; kk++) {
    const int kkq = kk * 4 + quad;
    const int qoff = ((kkq & 8) | ((kkq ^ (l16 & 7)) & 7)) * 8;
    bf16x8 af = __builtin_bit_cast(bf16x8, *(const s16x8*)&qt[(w * 16 + l16) * 128 + qoff]);
    #pragma unroll
    for (int nt = 0; nt < 8; nt++) {
      const int kc = kk * 4 + quad;
      const int mo = ((kc & 8) | ((kc ^ (l16 & 7)) & 7)) * 8;
      bf16x8 mb = __builtin_bit_cast(bf16x8, *(const s16x8*)&MT[(nt * 16 + l16) * 128 + mo]);
      oacc[nt] = __builtin_amdgcn_mfma_f32_16x16x32_bf16(af, mb, oacc[nt], 0, 0, 0);
    }
  }
  __builtin_amdgcn_s_setprio(0);

  // epilogue: of = oacc / dent, f16
  #pragma unroll
  for (int rg = 0; rg < 4; rg++) {
    int r = w * 16 + quad * 4 + rg;
    float inv = 1.0f / dent[r];
    #pragma unroll
    for (int nt = 0; nt < 8; nt++) {
      int c = nt * 16 + l16;
      float v = oacc[nt][rg] * inv;
      size_t oi = (size_t)(qi * 64 + r) * DIMM + h * DH + c;
      of16[oi] = __builtin_bit_cast(u16, (_Float16)v);
    }
  }
}

// -------------------------------------------------------------------------
extern "C" void kernel_launch(void* const* d_in, const int* in_sizes, int n_in,
                              void* d_out, int out_size, void* d_ws, size_t ws_size,
                              hipStream_t stream) {
  const float* hs = (const float*)d_in[0];
  const float* fc = (const float*)d_in[1];
  const float* fs = (const float*)d_in[2];
  const float* Wq = (const float*)d_in[3];
  const float* bq = (const float*)d_in[4];
  const float* Wk = (const float*)d_in[5];
  const float* bk = (const float*)d_in[6];
  const float* Wv = (const float*)d_in[7];
  const float* bv = (const float*)d_in[8];
  const float* Wo = (const float*)d_in[9];
  const float* bo = (const float*)d_in[10];
  const float* gq = (const float*)d_in[11];
  const float* gk = (const float*)d_in[12];

  char* p = (char*)d_ws;
  auto alloc = [&](size_t bytes) {
    char* r = p; p += (bytes + 255) & ~(size_t)255; return r;
  };
  u16* WTh = (u16*)alloc((size_t)4 * DIMM * DIMM * 2);
  u16* WTl = (u16*)alloc((size_t)4 * DIMM * DIMM * 2);
  u16* hsh = (u16*)alloc((size_t)SQ * DIMM * 2);   // reused later as of16
  u16* hsl = (u16*)alloc((size_t)SQ * DIMM * 2);   // reused later as MTg
  float* qkv = (float*)alloc((size_t)SQ * QS * 4);
  u16* qbf = (u16*)alloc((size_t)NH * SQ * DH * 2);
  u16* kbf = (u16*)alloc((size_t)NH * SQ * DH * 2);
  u16* vbfT = (u16*)alloc((size_t)NH * NKB * DH * 64 * 2);
  float* qb = (float*)alloc((size_t)NH * NQB * DH * 4);
  float* kb = (float*)alloc((size_t)NH * NKB * DH * 4);
  int* sel = (int*)alloc((size_t)NH * NQB * 8 * 4);
  float* KV = (float*)alloc((size_t)NH * NKB * DH * DH * 4);
  float* slk = (float*)alloc((size_t)NH * NKB * DH * 4);
  float* KVtot = (float*)alloc((size_t)NH * DH * DH * 4);
  float* sltot = (float*)alloc((size_t)NH * DH * 4);

  float* qf = qkv;
  float* kf = qkv + DIMM;

  prep_all<<<1536 + 2304, 256, 0, stream>>>(hs, hsh, hsl, Wq, Wk, Wv, Wo, WTh, WTl);

  gemm3_k<<<dim3(36, 16), 512, 0, stream>>>(hsh, hsl, WTh, WTl, bq, bk, bv, qkv, vbfT);

  norm_rope_k<<<dim3(SQ, 2), 256, 0, stream>>>(qkv, gq, gk, fc, fs, qbf, kbf);
  kvmeans_k<<<dim3(NKB + NQB + NKB, NH), 256, 0, stream>>>(qf, kf, vbfT, KV, slk, qb, kb);
  kvtot_topk_k<<<dim3(64 + NQB, NH), 256, 0, stream>>>(KV, slk, qb, kb, KVtot, sltot, sel);

  // hs staging buffers are dead now; reuse hsh as f16 attention output,
  // hsl as precomputed MT buffer.
  u16* of16 = hsh;
  u16* MTg = hsl;
  mt_k<<<192, 256, 0, stream>>>(sel, KV, KVtot, MTg);
  attn_k<<<384, 256, 0, stream>>>(qbf, kbf, vbfT, sel, slk, sltot, MTg, of16);

  const u16* WTo = WTh + (size_t)3 * DIMM * DIMM;   // f16 W_o^T
  gemm_o<<<dim3(12, 32), 256, 0, stream>>>(of16, WTo, bo, (float*)d_out);
}